// Round 5
// baseline (736.234 us; speedup 1.0000x reference)
//
#include <hip/hip_runtime.h>
#include <hip/hip_bf16.h>

#define S_SEQ 8192
#define D_DIM 1024
#define NCLS 7

typedef __bf16 bf16x8 __attribute__((ext_vector_type(8)));
typedef float f32x4 __attribute__((ext_vector_type(4)));

typedef const __attribute__((address_space(1))) void* gas_ptr;
typedef __attribute__((address_space(3))) void* las_ptr;
#define GLL(gp, lp) __builtin_amdgcn_global_load_lds((gas_ptr)(const void*)(gp), (las_ptr)(void*)(lp), 16, 0, 0)

__device__ __forceinline__ unsigned short f2bf(float f) {
    unsigned int u = __builtin_bit_cast(unsigned int, f);
    u = (u + 0x7FFFu + ((u >> 16) & 1u)) >> 16;
    return (unsigned short)u;
}
__device__ __forceinline__ float bf2f(unsigned short h) {
    unsigned int u = ((unsigned int)h) << 16;
    return __builtin_bit_cast(float, u);
}

// ---------------- elementwise fp32 -> bf16 ----------------
__global__ __launch_bounds__(256) void k_f32_to_bf16(const float* __restrict__ src,
                                                     unsigned short* __restrict__ dst, int n4) {
    int i = blockIdx.x * 256 + threadIdx.x;
    if (i >= n4) return;
    float4 v = ((const float4*)src)[i];
    ushort4 o;
    o.x = f2bf(v.x); o.y = f2bf(v.y); o.z = f2bf(v.z); o.w = f2bf(v.w);
    ((ushort4*)dst)[i] = o;
}

// ---------------- sum of two fp32 arrays -> bf16 ----------------
__global__ __launch_bounds__(256) void k_sum2_bf16(const float* __restrict__ a,
                                                   const float* __restrict__ b,
                                                   unsigned short* __restrict__ dst, int n4) {
    int i = blockIdx.x * 256 + threadIdx.x;
    if (i >= n4) return;
    float4 va = ((const float4*)a)[i];
    float4 vb = ((const float4*)b)[i];
    ushort4 o;
    o.x = f2bf(va.x + vb.x); o.y = f2bf(va.y + vb.y);
    o.z = f2bf(va.z + vb.z); o.w = f2bf(va.w + vb.w);
    ((ushort4*)dst)[i] = o;
}

// ---------------- transpose fp32 [R][C] -> bf16 [C][R] ----------------
__global__ __launch_bounds__(256) void k_transpose_f32_bf16(const float* __restrict__ src,
                                                            unsigned short* __restrict__ dst,
                                                            int R, int C) {
    __shared__ unsigned short t[64][80];
    int r0 = blockIdx.x * 64, c0 = blockIdx.y * 64;
    int tid = threadIdx.x;
    int rr = tid >> 4, cc = (tid & 15) << 2;
#pragma unroll
    for (int p = 0; p < 4; ++p) {
        int r = rr + p * 16;
        float4 v = *(const float4*)(src + (size_t)(r0 + r) * C + c0 + cc);
        t[cc + 0][r] = f2bf(v.x);
        t[cc + 1][r] = f2bf(v.y);
        t[cc + 2][r] = f2bf(v.z);
        t[cc + 3][r] = f2bf(v.w);
    }
    __syncthreads();
    int wr = tid >> 3, wc = (tid & 7) << 3;
#pragma unroll
    for (int p = 0; p < 2; ++p) {
        int c = wr + p * 32;
        uint4 v8 = *(const uint4*)&t[c][wc];
        *(uint4*)(dst + (size_t)(c0 + c) * R + r0 + wc) = v8;
    }
}

// ---------------- transpose bf16 [R][C] -> bf16 [C][R] ----------------
__global__ __launch_bounds__(256) void k_transpose_bf16(const unsigned short* __restrict__ src,
                                                        unsigned short* __restrict__ dst,
                                                        int R, int C) {
    __shared__ unsigned short t[64][80];
    int r0 = blockIdx.x * 64, c0 = blockIdx.y * 64;
    int tid = threadIdx.x;
    int rr = tid >> 3, cc = (tid & 7) << 3;
#pragma unroll
    for (int p = 0; p < 2; ++p) {
        int r = rr + p * 32;
        uint4 v = *(const uint4*)(src + (size_t)(r0 + r) * C + c0 + cc);
        const unsigned short* pv = (const unsigned short*)&v;
#pragma unroll
        for (int i = 0; i < 8; ++i) t[cc + i][r] = pv[i];
    }
    __syncthreads();
    int wr = tid >> 3, wc = (tid & 7) << 3;
#pragma unroll
    for (int p = 0; p < 2; ++p) {
        int c = wr + p * 32;
        uint4 v8 = *(const uint4*)&t[c][wc];
        *(uint4*)(dst + (size_t)(c0 + c) * R + r0 + wc) = v8;
    }
}

// ---------------- LayerNorm row kernel (strided input): bf16 out ----------------
__global__ __launch_bounds__(256) void k_ln_bf16(const float* __restrict__ Y, int ldy,
                                                 const float* __restrict__ bias,
                                                 const float* __restrict__ g,
                                                 const float* __restrict__ beta,
                                                 unsigned short* __restrict__ out) {
    __shared__ float red[8];
    int row = blockIdx.x, tid = threadIdx.x;
    float4 y = *(const float4*)(Y + (size_t)row * ldy + tid * 4);
    float4 b4 = *(const float4*)(bias + tid * 4);
    y.x += b4.x; y.y += b4.y; y.z += b4.z; y.w += b4.w;
    float s = y.x + y.y + y.z + y.w;
    float s2 = y.x * y.x + y.y * y.y + y.z * y.z + y.w * y.w;
#pragma unroll
    for (int o = 32; o; o >>= 1) { s += __shfl_down(s, o); s2 += __shfl_down(s2, o); }
    int lane = tid & 63, wv = tid >> 6;
    if (lane == 0) { red[wv] = s; red[4 + wv] = s2; }
    __syncthreads();
    s = red[0] + red[1] + red[2] + red[3];
    s2 = red[4] + red[5] + red[6] + red[7];
    float m = s * (1.0f / D_DIM);
    float var = s2 * (1.0f / D_DIM) - m * m;
    float rs = rsqrtf(var + 1e-5f);
    float4 g4 = *(const float4*)(g + tid * 4);
    float4 be4 = *(const float4*)(beta + tid * 4);
    ushort4 o4;
    o4.x = f2bf((y.x - m) * rs * g4.x + be4.x);
    o4.y = f2bf((y.y - m) * rs * g4.y + be4.y);
    o4.z = f2bf((y.z - m) * rs * g4.z + be4.z);
    o4.w = f2bf((y.w - m) * rs * g4.w + be4.w);
    *(ushort4*)(out + (size_t)row * D_DIM + tid * 4) = o4;
}

// ---------------- combine per-tile stats: rmax, rrecip ----------------
__global__ __launch_bounds__(256) void k_stats_reduce(const float* __restrict__ pmax,
                                                      const float* __restrict__ psum,
                                                      float* __restrict__ rmax,
                                                      float* __restrict__ rrecip, int nblk) {
    int row = blockIdx.x * 4 + (threadIdx.x >> 6);
    int lane = threadIdx.x & 63;
    const float* pm = pmax + (size_t)row * nblk;
    const float* ps = psum + (size_t)row * nblk;
    float m = -3.4e38f;
    for (int j = lane; j < nblk; j += 64) m = fmaxf(m, pm[j]);
#pragma unroll
    for (int mk = 32; mk; mk >>= 1) m = fmaxf(m, __shfl_xor(m, mk));
    float s = 0.0f;
    for (int j = lane; j < nblk; j += 64) s += ps[j] * __expf(pm[j] - m);
#pragma unroll
    for (int mk = 32; mk; mk >>= 1) s += __shfl_xor(s, mk);
    if (lane == 0) { rmax[row] = m; rrecip[row] = 1.0f / s; }
}

// ------- normalize: bf16 logits -> fp32 attn + bf16 At -------
__global__ __launch_bounds__(256) void k_norm_transpose(const unsigned short* __restrict__ src16,
                                                        float* __restrict__ attn,
                                                        const float* __restrict__ rmax,
                                                        const float* __restrict__ rrecip,
                                                        unsigned short* __restrict__ At) {
    __shared__ unsigned short t[64][80];
    int t0 = blockIdx.x * 64, s0 = blockIdx.y * 64;
    int tid = threadIdx.x;
    int rr = tid >> 4, cc = (tid & 15) << 2;
#pragma unroll
    for (int p = 0; p < 4; ++p) {
        int r = rr + p * 16;
        float m = rmax[t0 + r], rc = rrecip[t0 + r];
        size_t off = (size_t)(t0 + r) * S_SEQ + s0 + cc;
        ushort4 u = *(const ushort4*)(src16 + off);
        float4 v;
        v.x = __expf(bf2f(u.x) - m) * rc;
        v.y = __expf(bf2f(u.y) - m) * rc;
        v.z = __expf(bf2f(u.z) - m) * rc;
        v.w = __expf(bf2f(u.w) - m) * rc;
        *(float4*)(attn + off) = v;
        t[cc + 0][r] = f2bf(v.x);
        t[cc + 1][r] = f2bf(v.y);
        t[cc + 2][r] = f2bf(v.z);
        t[cc + 3][r] = f2bf(v.w);
    }
    __syncthreads();
    int wr = tid >> 3, wc = (tid & 7) << 3;
#pragma unroll
    for (int p = 0; p < 2; ++p) {
        int c = wr + p * 32;
        uint4 v8 = *(const uint4*)&t[c][wc];
        *(uint4*)(At + (size_t)(s0 + c) * S_SEQ + t0 + wc) = v8;
    }
}

// ---------------- classifier: c = x @ Wc + bc ----------------
__global__ __launch_bounds__(256) void k_classifier(const float* __restrict__ x,
                                                    const float* __restrict__ Wc,
                                                    const float* __restrict__ bc,
                                                    float* __restrict__ outc) {
    __shared__ float red[4][NCLS];
    int row = blockIdx.x, tid = threadIdx.x;
    float4 xv = *(const float4*)(x + (size_t)row * D_DIM + tid * 4);
    const float* w0 = Wc + (size_t)(tid * 4) * NCLS;
    float acc[NCLS];
#pragma unroll
    for (int j = 0; j < NCLS; ++j)
        acc[j] = xv.x * w0[j] + xv.y * w0[NCLS + j] + xv.z * w0[2 * NCLS + j] + xv.w * w0[3 * NCLS + j];
#pragma unroll
    for (int j = 0; j < NCLS; ++j)
#pragma unroll
        for (int o = 32; o; o >>= 1) acc[j] += __shfl_down(acc[j], o);
    int lane = tid & 63, wv = tid >> 6;
    if (lane == 0) {
#pragma unroll
        for (int j = 0; j < NCLS; ++j) red[wv][j] = acc[j];
    }
    __syncthreads();
    if (tid < NCLS) {
        float s = red[0][tid] + red[1][tid] + red[2][tid] + red[3][tid];
        outc[(size_t)row * NCLS + tid] = s + bc[tid];
    }
}

// ============ pipelined bf16 GEMM: C[M,N] = scale*A[M,K]*B[N,K]^T (+bias) ============
// BM=256, BK=32, 512 threads (8 waves), NSLOT LDS buffers with (NSLOT-1)-tiles-ahead
// prefetch and counted vmcnt, LDS XOR swizzle via inverse-swizzled global source,
// setprio around MFMA. XCD mapping: bn partitioned across 8 XCDs (B panel L2-resident),
// bn-local fastest then bm (A panel reused by npx co-resident blocks). Optional
// split-K (template SK: sk0 -> C0, sk1 -> C1), bf16 output (Cb), fused softmax stats.
template<int BN, int WM, int WN, int NSLOT, int SK>
__global__ __launch_bounds__(512) void k_gemm_big(const unsigned short* __restrict__ A,
                                                  const unsigned short* __restrict__ B,
                                                  float* __restrict__ C0,
                                                  float* __restrict__ C1,
                                                  unsigned short* __restrict__ Cb,
                                                  int M, int N, int K,
                                                  float scale,
                                                  const float* __restrict__ bias,
                                                  float* __restrict__ pmax,
                                                  float* __restrict__ psum) {
    constexpr int MREP = 256 / WM / 16;
    constexpr int NREP = BN / WN / 16;
    constexpr int PHASES = MREP / 4;
    constexpr int BISS = BN / 128;
    constexpr int TISS = 2 + BISS;
    constexpr int DEPTH = NSLOT - 1;
    constexpr int ASLOT = 256 * 32;
    constexpr int BSLOT = BN * 32;
    constexpr int SLOT = ASLOT + BSLOT;
    __shared__ unsigned short lds[NSLOT * SLOT];

    const int tid = threadIdx.x;
    const int lane = tid & 63;
    const int wid = tid >> 6;
    const int wm = wid / WN;
    const int wn = wid % WN;
    const int fm = lane & 15;
    const int g = lane >> 4;

    // XCD mapping: bn partitioned across XCDs (requires nbn%8==0, nwg%8==0)
    const int nbm = M >> 8;
    const int nbn = N / BN;
    int bm, bn, sk;
    if (((nbn & 7) == 0) && ((gridDim.x & 7) == 0)) {
        const int npx = nbn >> 3;
        const int xcd = blockIdx.x & 7;
        const int c = blockIdx.x >> 3;
        bn = xcd * npx + (c % npx);
        const int r = c / npx;
        bm = r % nbm;
        sk = r / nbm;
    } else {
        bm = blockIdx.x / nbn;
        bn = blockIdx.x % nbn;
        sk = 0;
    }
    const int brow = bm << 8;
    const int bcol = bn * BN;

    const int Ksub = K / SK;
    const int NT = Ksub >> 5;
    float* __restrict__ C = (sk == 0) ? C0 : C1;

    // ----- staging (inverse-swizzled global source, linear LDS dest) -----
    const int arow = tid >> 2;
    const int scb = ((tid & 3) << 4) ^ ((arow & 6) << 3);
    const unsigned short* gA = A + (size_t)(brow + arow) * K + sk * Ksub + (scb >> 1);
    const unsigned short* gB = B + (size_t)(bcol + arow) * K + sk * Ksub + (scb >> 1);
    unsigned short* lA = lds + tid * 8;
    unsigned short* lB = lds + ASLOT + tid * 8;
    const size_t rows128 = (size_t)128 * K;

    auto stageA = [&](int kt, int slot) {
        const unsigned short* s = gA + ((size_t)kt << 5);
        unsigned short* d = lA + slot * SLOT;
        GLL(s, d);
        GLL(s + rows128, d + 4096);
    };
    auto stageB = [&](int kt, int slot) {
        const unsigned short* s = gB + ((size_t)kt << 5);
        unsigned short* d = lB + slot * SLOT;
#pragma unroll
        for (int h = 0; h < BISS; ++h)
            GLL(s + (size_t)h * rows128, d + h * 4096);
    };

    // ----- fragment read bases (swizzled) -----
    const int cbf = (((g << 4) ^ ((fm & 6) << 3)) >> 1);
    const unsigned short* fA = lds + (wm * (256 / WM) + fm) * 32 + cbf;
    const unsigned short* fB = lds + ASLOT + (wn * (BN / WN) + fm) * 32 + cbf;

    f32x4 acc[MREP][NREP] = {};

    // prologue: stage tiles 0..DEPTH-1
#pragma unroll
    for (int p = 0; p < DEPTH; ++p) { stageA(p, p); stageB(p, p); }
    asm volatile("s_waitcnt vmcnt(%0)" :: "n"((DEPTH - 1) * TISS) : "memory");
    __builtin_amdgcn_s_barrier();

    for (int t = 0; t < NT; ++t) {
        const int slot = t % NSLOT;
        const unsigned short* sA = fA + slot * SLOT;
        const unsigned short* sB = fB + slot * SLOT;
        const int pslot = (t + DEPTH) % NSLOT;
        const bool pf = (t + DEPTH) < NT;

        bf16x8 bfr[NREP];
        bf16x8 afr[4];
#pragma unroll
        for (int i = 0; i < 4; ++i) afr[i] = *(const bf16x8*)(sA + i * 512);
#pragma unroll
        for (int j = 0; j < NREP; ++j) bfr[j] = *(const bf16x8*)(sB + j * 512);
        if (pf) {
            stageA(t + DEPTH, pslot);
            if (PHASES == 1) stageB(t + DEPTH, pslot);
        }
        __builtin_amdgcn_s_barrier();
        asm volatile("s_waitcnt lgkmcnt(0)" ::: "memory");
        __builtin_amdgcn_s_setprio(1);
#pragma unroll
        for (int i = 0; i < 4; ++i)
#pragma unroll
            for (int j = 0; j < NREP; ++j)
                acc[i][j] = __builtin_amdgcn_mfma_f32_16x16x32_bf16(afr[i], bfr[j], acc[i][j], 0, 0, 0);
        __builtin_amdgcn_s_setprio(0);
        __builtin_amdgcn_s_barrier();

        if (PHASES == 2) {
#pragma unroll
            for (int i = 0; i < 4; ++i) afr[i] = *(const bf16x8*)(sA + (i + 4) * 512);
            if (pf) stageB(t + DEPTH, pslot);
            __builtin_amdgcn_s_barrier();
            asm volatile("s_waitcnt lgkmcnt(0)" ::: "memory");
            __builtin_amdgcn_s_setprio(1);
#pragma unroll
            for (int i = 0; i < 4; ++i)
#pragma unroll
                for (int j = 0; j < NREP; ++j)
                    acc[(i + 4) % MREP][j] = __builtin_amdgcn_mfma_f32_16x16x32_bf16(afr[i], bfr[j], acc[(i + 4) % MREP][j], 0, 0, 0);
            __builtin_amdgcn_s_setprio(0);
        }

        if (t + 1 < NT) {
            if constexpr (DEPTH == 3) {
                if (t + 3 < NT)
                    asm volatile("s_waitcnt vmcnt(%0)" :: "n"(2 * TISS) : "memory");
                else if (t + 2 < NT)
                    asm volatile("s_waitcnt vmcnt(%0)" :: "n"(TISS) : "memory");
                else
                    asm volatile("s_waitcnt vmcnt(0)" ::: "memory");
            } else {
                if (t + 2 < NT)
                    asm volatile("s_waitcnt vmcnt(%0)" :: "n"(TISS) : "memory");
                else
                    asm volatile("s_waitcnt vmcnt(0)" ::: "memory");
            }
        }
        __builtin_amdgcn_s_barrier();
    }

    // ---- fused softmax-stat epilogue (per-row max & sum-exp over 64 cols) ----
    if (psum) {
        const int nblk = N >> 6;
        const int cblk = (bcol >> 6) + wn;
#pragma unroll
        for (int i = 0; i < MREP; ++i) {
#pragma unroll
            for (int r = 0; r < 4; ++r) {
                float v0 = acc[i][0][r] * scale, v1 = acc[i][1][r] * scale;
                float v2 = acc[i][2][r] * scale, v3 = acc[i][3][r] * scale;
                float mv = fmaxf(fmaxf(v0, v1), fmaxf(v2, v3));
#pragma unroll
                for (int mk = 1; mk < 16; mk <<= 1) mv = fmaxf(mv, __shfl_xor(mv, mk));
                float sv = __expf(v0 - mv) + __expf(v1 - mv) + __expf(v2 - mv) + __expf(v3 - mv);
#pragma unroll
                for (int mk = 1; mk < 16; mk <<= 1) sv += __shfl_xor(sv, mk);
                if (fm == 0) {
                    int row = brow + wm * (256 / WM) + i * 16 + (g << 2) + r;
                    pmax[(size_t)row * nblk + cblk] = mv;
                    psum[(size_t)row * nblk + cblk] = sv;
                }
            }
        }
    }

    // ---- store ----
    const int r0 = g << 2;
    if (Cb) {
#pragma unroll
        for (int i = 0; i < MREP; ++i) {
#pragma unroll
            for (int j = 0; j < NREP; ++j) {
                int col = bcol + wn * (BN / WN) + j * 16 + fm;
#pragma unroll
                for (int r = 0; r < 4; ++r) {
                    int row = brow + wm * (256 / WM) + i * 16 + r0 + r;
                    Cb[(size_t)row * N + col] = f2bf(acc[i][j][r] * scale);
                }
            }
        }
    } else {
#pragma unroll
        for (int i = 0; i < MREP; ++i) {
#pragma unroll
            for (int j = 0; j < NREP; ++j) {
                int col = bcol + wn * (BN / WN) + j * 16 + fm;
                float badd = bias ? bias[col] : 0.0f;
#pragma unroll
                for (int r = 0; r < 4; ++r) {
                    int row = brow + wm * (256 / WM) + i * 16 + r0 + r;
                    C[(size_t)row * N + col] = acc[i][j][r] * scale + badd;
                }
            }
        }
    }
}

extern "C" void kernel_launch(void* const* d_in, const int* in_sizes, int n_in,
                              void* d_out, int out_size, void* d_ws, size_t ws_size,
                              hipStream_t stream) {
    const float* x     = (const float*)d_in[0];
    const float* Wq    = (const float*)d_in[1];
    const float* bq    = (const float*)d_in[2];
    const float* gq    = (const float*)d_in[3];
    const float* betaq = (const float*)d_in[4];
    const float* Wk    = (const float*)d_in[5];
    const float* bk    = (const float*)d_in[6];
    const float* gk    = (const float*)d_in[7];
    const float* betak = (const float*)d_in[8];
    const float* Wv    = (const float*)d_in[9];
    const float* bv    = (const float*)d_in[10];
    const float* gv    = (const float*)d_in[11];
    const float* betav = (const float*)d_in[12];
    const float* Wo    = (const float*)d_in[13];
    const float* bo    = (const float*)d_in[14];
    const float* Wc    = (const float*)d_in[15];
    const float* bc    = (const float*)d_in[16];

    float* out_o    = (float*)d_out;
    float* out_c    = out_o + (size_t)S_SEQ * D_DIM;
    float* out_attn = out_c + (size_t)S_SEQ * NCLS;

    char* cur = (char*)d_ws;
    auto alloc = [&](size_t bytes) {
        char* p = cur;
        cur += (bytes + 255) & ~(size_t)255;
        return p;
    };
    const size_t SD2 = (size_t)S_SEQ * D_DIM * 2;
    const size_t DD2 = (size_t)D_DIM * D_DIM * 2;
    unsigned short* xb   = (unsigned short*)alloc(SD2);
    unsigned short* wqkv = (unsigned short*)alloc(3 * DD2);
    unsigned short* wto  = (unsigned short*)alloc(DD2);
    unsigned short* qb   = (unsigned short*)alloc(SD2);
    unsigned short* kb   = (unsigned short*)alloc(SD2);
    unsigned short* vb   = (unsigned short*)alloc(SD2);
    unsigned short* Vt   = (unsigned short*)alloc(SD2);
    unsigned short* valb = (unsigned short*)alloc(SD2);
    float* rmax   = (float*)alloc((size_t)S_SEQ * 4);
    float* rrecip = (float*)alloc((size_t)S_SEQ * 4);
    unsigned short* At = (unsigned short*)alloc((size_t)S_SEQ * S_SEQ * 2);
    unsigned short* Lb = (unsigned short*)alloc((size_t)S_SEQ * S_SEQ * 2);

    // overlays: pmax/psum over xb (dead after QKV GEMM); split-K partial over qb+kb
    // (dead after QK^T; 8192*1024 fp32 = 32 MB = qb+kb exactly).
    float* pmax = (float*)xb;
    float* psum = pmax + (size_t)S_SEQ * 128;
    float* part1 = (float*)qb;

    const int n4_xd = S_SEQ * D_DIM / 4;

    // x -> bf16
    k_f32_to_bf16<<<n4_xd / 256, 256, 0, stream>>>(x, xb, n4_xd);
    // weight transposes: fp32 [K][N] -> bf16 [N][K]; q/k/v concatenated along N
    k_transpose_f32_bf16<<<dim3(16, 16), 256, 0, stream>>>(Wq, wqkv, D_DIM, D_DIM);
    k_transpose_f32_bf16<<<dim3(16, 16), 256, 0, stream>>>(Wk, wqkv + (size_t)D_DIM * D_DIM, D_DIM, D_DIM);
    k_transpose_f32_bf16<<<dim3(16, 16), 256, 0, stream>>>(Wv, wqkv + (size_t)2 * D_DIM * D_DIM, D_DIM, D_DIM);
    k_transpose_f32_bf16<<<dim3(16, 16), 256, 0, stream>>>(Wo, wto, D_DIM, D_DIM);
    // classifier (independent)
    k_classifier<<<S_SEQ, 256, 0, stream>>>(x, Wc, bc, out_c);

    // fused QKV GEMM: [8192][3072] fp32 into out_attn scratch
    float* qkv = out_attn;
    k_gemm_big<128, 4, 2, 4, 1><<<(S_SEQ / 256) * (3 * D_DIM / 128), 512, 0, stream>>>(
        xb, wqkv, qkv, nullptr, nullptr, S_SEQ, 3 * D_DIM, D_DIM, 1.0f, nullptr, nullptr, nullptr);
    // per-chain LayerNorm -> bf16
    k_ln_bf16<<<S_SEQ, 256, 0, stream>>>(qkv,              3 * D_DIM, bq, gq, betaq, qb);
    k_ln_bf16<<<S_SEQ, 256, 0, stream>>>(qkv + D_DIM,      3 * D_DIM, bk, gk, betak, kb);
    k_ln_bf16<<<S_SEQ, 256, 0, stream>>>(qkv + 2 * D_DIM,  3 * D_DIM, bv, gv, betav, vb);

    // V^T for the A^T V GEMM
    k_transpose_bf16<<<dim3(S_SEQ / 64, D_DIM / 64), 256, 0, stream>>>(vb, Vt, S_SEQ, D_DIM);

    // logits = q k^T / 32 -> bf16 Lb, fused per-tile softmax stats
    k_gemm_big<256, 2, 4, 4, 1><<<(S_SEQ / 256) * (S_SEQ / 256), 512, 0, stream>>>(
        qb, kb, nullptr, nullptr, Lb, S_SEQ, S_SEQ, D_DIM, 0.03125f, nullptr, pmax, psum);

    // combine stats, then normalize -> fp32 attention output + bf16 At
    k_stats_reduce<<<S_SEQ / 4, 256, 0, stream>>>(pmax, psum, rmax, rrecip, S_SEQ / 64);
    k_norm_transpose<<<dim3(S_SEQ / 64, S_SEQ / 64), 256, 0, stream>>>(
        Lb, out_attn, rmax, rrecip, At);

    // values = A^T V: split-K=2, 3-slot LDS (72 KB -> 2 blocks/CU), then sum -> bf16
    k_gemm_big<128, 4, 2, 3, 2><<<2 * (S_SEQ / 256) * (D_DIM / 128), 512, 0, stream>>>(
        At, Vt, out_o, part1, nullptr, S_SEQ, D_DIM, S_SEQ, 1.0f, nullptr, nullptr, nullptr);
    k_sum2_bf16<<<n4_xd / 256, 256, 0, stream>>>(out_o, part1, valb, n4_xd);

    // o = values @ Wo + bo
    k_gemm_big<128, 4, 2, 4, 1><<<(S_SEQ / 256) * (D_DIM / 128), 512, 0, stream>>>(
        valb, wto, out_o, nullptr, nullptr, S_SEQ, D_DIM, D_DIM, 1.0f, bo, nullptr, nullptr);
}

// Round 6
// 620.104 us; speedup vs baseline: 1.1873x; 1.1873x over previous
//
#include <hip/hip_runtime.h>
#include <hip/hip_bf16.h>

#define S_SEQ 8192
#define D_DIM 1024
#define NCLS 7

typedef __bf16 bf16x8 __attribute__((ext_vector_type(8)));
typedef float f32x4 __attribute__((ext_vector_type(4)));

typedef const __attribute__((address_space(1))) void* gas_ptr;
typedef __attribute__((address_space(3))) void* las_ptr;
#define GLL(gp, lp) __builtin_amdgcn_global_load_lds((gas_ptr)(const void*)(gp), (las_ptr)(void*)(lp), 16, 0, 0)

__device__ __forceinline__ unsigned short f2bf(float f) {
    unsigned int u = __builtin_bit_cast(unsigned int, f);
    u = (u + 0x7FFFu + ((u >> 16) & 1u)) >> 16;
    return (unsigned short)u;
}
__device__ __forceinline__ float bf2f(unsigned short h) {
    unsigned int u = ((unsigned int)h) << 16;
    return __builtin_bit_cast(float, u);
}

// ---------------- elementwise fp32 -> bf16 ----------------
__global__ __launch_bounds__(256) void k_f32_to_bf16(const float* __restrict__ src,
                                                     unsigned short* __restrict__ dst, int n4) {
    int i = blockIdx.x * 256 + threadIdx.x;
    if (i >= n4) return;
    float4 v = ((const float4*)src)[i];
    ushort4 o;
    o.x = f2bf(v.x); o.y = f2bf(v.y); o.z = f2bf(v.z); o.w = f2bf(v.w);
    ((ushort4*)dst)[i] = o;
}

// ---------------- transpose fp32 [R][C] -> bf16 [C][R] ----------------
__global__ __launch_bounds__(256) void k_transpose_f32_bf16(const float* __restrict__ src,
                                                            unsigned short* __restrict__ dst,
                                                            int R, int C) {
    __shared__ unsigned short t[64][80];
    int r0 = blockIdx.x * 64, c0 = blockIdx.y * 64;
    int tid = threadIdx.x;
    int rr = tid >> 4, cc = (tid & 15) << 2;
#pragma unroll
    for (int p = 0; p < 4; ++p) {
        int r = rr + p * 16;
        float4 v = *(const float4*)(src + (size_t)(r0 + r) * C + c0 + cc);
        t[cc + 0][r] = f2bf(v.x);
        t[cc + 1][r] = f2bf(v.y);
        t[cc + 2][r] = f2bf(v.z);
        t[cc + 3][r] = f2bf(v.w);
    }
    __syncthreads();
    int wr = tid >> 3, wc = (tid & 7) << 3;
#pragma unroll
    for (int p = 0; p < 2; ++p) {
        int c = wr + p * 32;
        uint4 v8 = *(const uint4*)&t[c][wc];
        *(uint4*)(dst + (size_t)(c0 + c) * R + r0 + wc) = v8;
    }
}

// ---------------- transpose bf16 [R][C] -> bf16 [C][R] ----------------
__global__ __launch_bounds__(256) void k_transpose_bf16(const unsigned short* __restrict__ src,
                                                        unsigned short* __restrict__ dst,
                                                        int R, int C) {
    __shared__ unsigned short t[64][80];
    int r0 = blockIdx.x * 64, c0 = blockIdx.y * 64;
    int tid = threadIdx.x;
    int rr = tid >> 3, cc = (tid & 7) << 3;
#pragma unroll
    for (int p = 0; p < 2; ++p) {
        int r = rr + p * 32;
        uint4 v = *(const uint4*)(src + (size_t)(r0 + r) * C + c0 + cc);
        const unsigned short* pv = (const unsigned short*)&v;
#pragma unroll
        for (int i = 0; i < 8; ++i) t[cc + i][r] = pv[i];
    }
    __syncthreads();
    int wr = tid >> 3, wc = (tid & 7) << 3;
#pragma unroll
    for (int p = 0; p < 2; ++p) {
        int c = wr + p * 32;
        uint4 v8 = *(const uint4*)&t[c][wc];
        *(uint4*)(dst + (size_t)(c0 + c) * R + r0 + wc) = v8;
    }
}

// ---------------- LayerNorm row kernel (strided input): bf16 out ----------------
__global__ __launch_bounds__(256) void k_ln_bf16(const float* __restrict__ Y, int ldy,
                                                 const float* __restrict__ bias,
                                                 const float* __restrict__ g,
                                                 const float* __restrict__ beta,
                                                 unsigned short* __restrict__ out) {
    __shared__ float red[8];
    int row = blockIdx.x, tid = threadIdx.x;
    float4 y = *(const float4*)(Y + (size_t)row * ldy + tid * 4);
    float4 b4 = *(const float4*)(bias + tid * 4);
    y.x += b4.x; y.y += b4.y; y.z += b4.z; y.w += b4.w;
    float s = y.x + y.y + y.z + y.w;
    float s2 = y.x * y.x + y.y * y.y + y.z * y.z + y.w * y.w;
#pragma unroll
    for (int o = 32; o; o >>= 1) { s += __shfl_down(s, o); s2 += __shfl_down(s2, o); }
    int lane = tid & 63, wv = tid >> 6;
    if (lane == 0) { red[wv] = s; red[4 + wv] = s2; }
    __syncthreads();
    s = red[0] + red[1] + red[2] + red[3];
    s2 = red[4] + red[5] + red[6] + red[7];
    float m = s * (1.0f / D_DIM);
    float var = s2 * (1.0f / D_DIM) - m * m;
    float rs = rsqrtf(var + 1e-5f);
    float4 g4 = *(const float4*)(g + tid * 4);
    float4 be4 = *(const float4*)(beta + tid * 4);
    ushort4 o4;
    o4.x = f2bf((y.x - m) * rs * g4.x + be4.x);
    o4.y = f2bf((y.y - m) * rs * g4.y + be4.y);
    o4.z = f2bf((y.z - m) * rs * g4.z + be4.z);
    o4.w = f2bf((y.w - m) * rs * g4.w + be4.w);
    *(ushort4*)(out + (size_t)row * D_DIM + tid * 4) = o4;
}

// ---------------- combine per-tile stats: rmax, rrecip ----------------
__global__ __launch_bounds__(256) void k_stats_reduce(const float* __restrict__ pmax,
                                                      const float* __restrict__ psum,
                                                      float* __restrict__ rmax,
                                                      float* __restrict__ rrecip, int nblk) {
    int row = blockIdx.x * 4 + (threadIdx.x >> 6);
    int lane = threadIdx.x & 63;
    const float* pm = pmax + (size_t)row * nblk;
    const float* ps = psum + (size_t)row * nblk;
    float m = -3.4e38f;
    for (int j = lane; j < nblk; j += 64) m = fmaxf(m, pm[j]);
#pragma unroll
    for (int mk = 32; mk; mk >>= 1) m = fmaxf(m, __shfl_xor(m, mk));
    float s = 0.0f;
    for (int j = lane; j < nblk; j += 64) s += ps[j] * __expf(pm[j] - m);
#pragma unroll
    for (int mk = 32; mk; mk >>= 1) s += __shfl_xor(s, mk);
    if (lane == 0) { rmax[row] = m; rrecip[row] = 1.0f / s; }
}

// ------- normalize: bf16 logits -> fp32 attn + bf16 At -------
__global__ __launch_bounds__(256) void k_norm_transpose(const unsigned short* __restrict__ src16,
                                                        float* __restrict__ attn,
                                                        const float* __restrict__ rmax,
                                                        const float* __restrict__ rrecip,
                                                        unsigned short* __restrict__ At) {
    __shared__ unsigned short t[64][80];
    int t0 = blockIdx.x * 64, s0 = blockIdx.y * 64;
    int tid = threadIdx.x;
    int rr = tid >> 4, cc = (tid & 15) << 2;
#pragma unroll
    for (int p = 0; p < 4; ++p) {
        int r = rr + p * 16;
        float m = rmax[t0 + r], rc = rrecip[t0 + r];
        size_t off = (size_t)(t0 + r) * S_SEQ + s0 + cc;
        ushort4 u = *(const ushort4*)(src16 + off);
        float4 v;
        v.x = __expf(bf2f(u.x) - m) * rc;
        v.y = __expf(bf2f(u.y) - m) * rc;
        v.z = __expf(bf2f(u.z) - m) * rc;
        v.w = __expf(bf2f(u.w) - m) * rc;
        *(float4*)(attn + off) = v;
        t[cc + 0][r] = f2bf(v.x);
        t[cc + 1][r] = f2bf(v.y);
        t[cc + 2][r] = f2bf(v.z);
        t[cc + 3][r] = f2bf(v.w);
    }
    __syncthreads();
    int wr = tid >> 3, wc = (tid & 7) << 3;
#pragma unroll
    for (int p = 0; p < 2; ++p) {
        int c = wr + p * 32;
        uint4 v8 = *(const uint4*)&t[c][wc];
        *(uint4*)(At + (size_t)(s0 + c) * S_SEQ + t0 + wc) = v8;
    }
}

// ---------------- classifier: c = x @ Wc + bc ----------------
__global__ __launch_bounds__(256) void k_classifier(const float* __restrict__ x,
                                                    const float* __restrict__ Wc,
                                                    const float* __restrict__ bc,
                                                    float* __restrict__ outc) {
    __shared__ float red[4][NCLS];
    int row = blockIdx.x, tid = threadIdx.x;
    float4 xv = *(const float4*)(x + (size_t)row * D_DIM + tid * 4);
    const float* w0 = Wc + (size_t)(tid * 4) * NCLS;
    float acc[NCLS];
#pragma unroll
    for (int j = 0; j < NCLS; ++j)
        acc[j] = xv.x * w0[j] + xv.y * w0[NCLS + j] + xv.z * w0[2 * NCLS + j] + xv.w * w0[3 * NCLS + j];
#pragma unroll
    for (int j = 0; j < NCLS; ++j)
#pragma unroll
        for (int o = 32; o; o >>= 1) acc[j] += __shfl_down(acc[j], o);
    int lane = tid & 63, wv = tid >> 6;
    if (lane == 0) {
#pragma unroll
        for (int j = 0; j < NCLS; ++j) red[wv][j] = acc[j];
    }
    __syncthreads();
    if (tid < NCLS) {
        float s = red[0][tid] + red[1][tid] + red[2][tid] + red[3][tid];
        outc[(size_t)row * NCLS + tid] = s + bc[tid];
    }
}

// ============ pipelined bf16 GEMM: C[M,N] = scale*A[M,K]*B[N,K]^T (+bias) ============
// BM=256, BK=32, 512 threads (8 waves), NSLOT LDS buffers with (NSLOT-1)-tiles-ahead
// prefetch and counted vmcnt, LDS XOR swizzle via inverse-swizzled global source,
// setprio around MFMA. NSLOT=3 -> 73 KB LDS -> 2 blocks/CU (TLP covers barrier stalls).
// Mapping: USE_NPX=1 partitions bn across 8 XCDs (B panels L2-resident; only safe when
// npx>=4 so A panels have co-resident sharers); else chunked bijective round-robin
// (contiguous wg range per XCD -> A-panel reuse in-XCD). Output fp32 C (+bias) or
// bf16 Cb; optional fused softmax-stat epilogue (pmax/psum).
template<int BN, int WM, int WN, int NSLOT, int USE_NPX>
__global__ __launch_bounds__(512) void k_gemm_big(const unsigned short* __restrict__ A,
                                                  const unsigned short* __restrict__ B,
                                                  float* __restrict__ C,
                                                  unsigned short* __restrict__ Cb,
                                                  int M, int N, int K,
                                                  float scale,
                                                  const float* __restrict__ bias,
                                                  float* __restrict__ pmax,
                                                  float* __restrict__ psum) {
    constexpr int MREP = 256 / WM / 16;
    constexpr int NREP = BN / WN / 16;
    constexpr int PHASES = MREP / 4;
    constexpr int BISS = BN / 128;
    constexpr int TISS = 2 + BISS;
    constexpr int DEPTH = NSLOT - 1;
    constexpr int ASLOT = 256 * 32;
    constexpr int BSLOT = BN * 32;
    constexpr int SLOT = ASLOT + BSLOT;
    __shared__ unsigned short lds[NSLOT * SLOT];

    const int tid = threadIdx.x;
    const int lane = tid & 63;
    const int wid = tid >> 6;
    const int wm = wid / WN;
    const int wn = wid % WN;
    const int fm = lane & 15;
    const int g = lane >> 4;

    const int nbm = M >> 8;
    const int nbn = N / BN;
    int bm, bn;
    if (USE_NPX && ((nbn & 7) == 0) && ((gridDim.x & 7) == 0)) {
        // bn partitioned across XCDs; bn-local fastest so A panels are shared
        // by npx co-resident blocks within one XCD.
        const int npx = nbn >> 3;
        const int xcd = blockIdx.x & 7;
        const int c = blockIdx.x >> 3;
        bn = xcd * npx + (c % npx);
        bm = (c / npx) % nbm;
    } else if ((gridDim.x & 7) == 0) {
        // chunked bijective round-robin: XCD gets a contiguous wg range.
        int wg = (blockIdx.x & 7) * (gridDim.x >> 3) + (blockIdx.x >> 3);
        bm = wg / nbn;
        bn = wg % nbn;
    } else {
        bm = blockIdx.x / nbn;
        bn = blockIdx.x % nbn;
    }
    const int brow = bm << 8;
    const int bcol = bn * BN;

    const int NT = K >> 5;

    // ----- staging (inverse-swizzled global source, linear LDS dest) -----
    const int arow = tid >> 2;
    const int scb = ((tid & 3) << 4) ^ ((arow & 6) << 3);
    const unsigned short* gA = A + (size_t)(brow + arow) * K + (scb >> 1);
    const unsigned short* gB = B + (size_t)(bcol + arow) * K + (scb >> 1);
    unsigned short* lA = lds + tid * 8;
    unsigned short* lB = lds + ASLOT + tid * 8;
    const size_t rows128 = (size_t)128 * K;

    auto stageA = [&](int kt, int slot) {
        const unsigned short* s = gA + ((size_t)kt << 5);
        unsigned short* d = lA + slot * SLOT;
        GLL(s, d);
        GLL(s + rows128, d + 4096);
    };
    auto stageB = [&](int kt, int slot) {
        const unsigned short* s = gB + ((size_t)kt << 5);
        unsigned short* d = lB + slot * SLOT;
#pragma unroll
        for (int h = 0; h < BISS; ++h)
            GLL(s + (size_t)h * rows128, d + h * 4096);
    };

    // ----- fragment read bases (swizzled) -----
    const int cbf = (((g << 4) ^ ((fm & 6) << 3)) >> 1);
    const unsigned short* fA = lds + (wm * (256 / WM) + fm) * 32 + cbf;
    const unsigned short* fB = lds + ASLOT + (wn * (BN / WN) + fm) * 32 + cbf;

    f32x4 acc[MREP][NREP] = {};

    // prologue: stage tiles 0..DEPTH-1
#pragma unroll
    for (int p = 0; p < DEPTH; ++p) { stageA(p, p); stageB(p, p); }
    asm volatile("s_waitcnt vmcnt(%0)" :: "n"((DEPTH - 1) * TISS) : "memory");
    __builtin_amdgcn_s_barrier();

    for (int t = 0; t < NT; ++t) {
        const int slot = t % NSLOT;
        const unsigned short* sA = fA + slot * SLOT;
        const unsigned short* sB = fB + slot * SLOT;
        const int pslot = (t + DEPTH) % NSLOT;
        const bool pf = (t + DEPTH) < NT;

        bf16x8 bfr[NREP];
        bf16x8 afr[4];
#pragma unroll
        for (int i = 0; i < 4; ++i) afr[i] = *(const bf16x8*)(sA + i * 512);
#pragma unroll
        for (int j = 0; j < NREP; ++j) bfr[j] = *(const bf16x8*)(sB + j * 512);
        if (pf) {
            stageA(t + DEPTH, pslot);
            if (PHASES == 1) stageB(t + DEPTH, pslot);
        }
        __builtin_amdgcn_s_barrier();
        asm volatile("s_waitcnt lgkmcnt(0)" ::: "memory");
        __builtin_amdgcn_s_setprio(1);
#pragma unroll
        for (int i = 0; i < 4; ++i)
#pragma unroll
            for (int j = 0; j < NREP; ++j)
                acc[i][j] = __builtin_amdgcn_mfma_f32_16x16x32_bf16(afr[i], bfr[j], acc[i][j], 0, 0, 0);
        __builtin_amdgcn_s_setprio(0);
        __builtin_amdgcn_s_barrier();

        if (PHASES == 2) {
#pragma unroll
            for (int i = 0; i < 4; ++i) afr[i] = *(const bf16x8*)(sA + (i + 4) * 512);
            if (pf) stageB(t + DEPTH, pslot);
            __builtin_amdgcn_s_barrier();
            asm volatile("s_waitcnt lgkmcnt(0)" ::: "memory");
            __builtin_amdgcn_s_setprio(1);
#pragma unroll
            for (int i = 0; i < 4; ++i)
#pragma unroll
                for (int j = 0; j < NREP; ++j)
                    acc[(i + 4) % MREP][j] = __builtin_amdgcn_mfma_f32_16x16x32_bf16(afr[i], bfr[j], acc[(i + 4) % MREP][j], 0, 0, 0);
            __builtin_amdgcn_s_setprio(0);
        }

        if (t + 1 < NT) {
            if constexpr (DEPTH == 3) {
                if (t + 3 < NT)
                    asm volatile("s_waitcnt vmcnt(%0)" :: "n"(2 * TISS) : "memory");
                else if (t + 2 < NT)
                    asm volatile("s_waitcnt vmcnt(%0)" :: "n"(TISS) : "memory");
                else
                    asm volatile("s_waitcnt vmcnt(0)" ::: "memory");
            } else {
                if (t + 2 < NT)
                    asm volatile("s_waitcnt vmcnt(%0)" :: "n"(TISS) : "memory");
                else
                    asm volatile("s_waitcnt vmcnt(0)" ::: "memory");
            }
        }
        __builtin_amdgcn_s_barrier();
    }

    // ---- fused softmax-stat epilogue (per-row max & sum-exp over 64 cols) ----
    if (psum) {
        const int nblk = N >> 6;
        const int cblk = (bcol >> 6) + wn;
#pragma unroll
        for (int i = 0; i < MREP; ++i) {
#pragma unroll
            for (int r = 0; r < 4; ++r) {
                float v0 = acc[i][0][r] * scale, v1 = acc[i][1][r] * scale;
                float v2 = acc[i][2][r] * scale, v3 = acc[i][3][r] * scale;
                float mv = fmaxf(fmaxf(v0, v1), fmaxf(v2, v3));
#pragma unroll
                for (int mk = 1; mk < 16; mk <<= 1) mv = fmaxf(mv, __shfl_xor(mv, mk));
                float sv = __expf(v0 - mv) + __expf(v1 - mv) + __expf(v2 - mv) + __expf(v3 - mv);
#pragma unroll
                for (int mk = 1; mk < 16; mk <<= 1) sv += __shfl_xor(sv, mk);
                if (fm == 0) {
                    int row = brow + wm * (256 / WM) + i * 16 + (g << 2) + r;
                    pmax[(size_t)row * nblk + cblk] = mv;
                    psum[(size_t)row * nblk + cblk] = sv;
                }
            }
        }
    }

    // ---- store ----
    const int r0 = g << 2;
    if (Cb) {
#pragma unroll
        for (int i = 0; i < MREP; ++i) {
#pragma unroll
            for (int j = 0; j < NREP; ++j) {
                int col = bcol + wn * (BN / WN) + j * 16 + fm;
#pragma unroll
                for (int r = 0; r < 4; ++r) {
                    int row = brow + wm * (256 / WM) + i * 16 + r0 + r;
                    Cb[(size_t)row * N + col] = f2bf(acc[i][j][r] * scale);
                }
            }
        }
    } else {
#pragma unroll
        for (int i = 0; i < MREP; ++i) {
#pragma unroll
            for (int j = 0; j < NREP; ++j) {
                int col = bcol + wn * (BN / WN) + j * 16 + fm;
                float badd = bias ? bias[col] : 0.0f;
#pragma unroll
                for (int r = 0; r < 4; ++r) {
                    int row = brow + wm * (256 / WM) + i * 16 + r0 + r;
                    C[(size_t)row * N + col] = acc[i][j][r] * scale + badd;
                }
            }
        }
    }
}

extern "C" void kernel_launch(void* const* d_in, const int* in_sizes, int n_in,
                              void* d_out, int out_size, void* d_ws, size_t ws_size,
                              hipStream_t stream) {
    const float* x     = (const float*)d_in[0];
    const float* Wq    = (const float*)d_in[1];
    const float* bq    = (const float*)d_in[2];
    const float* gq    = (const float*)d_in[3];
    const float* betaq = (const float*)d_in[4];
    const float* Wk    = (const float*)d_in[5];
    const float* bk    = (const float*)d_in[6];
    const float* gk    = (const float*)d_in[7];
    const float* betak = (const float*)d_in[8];
    const float* Wv    = (const float*)d_in[9];
    const float* bv    = (const float*)d_in[10];
    const float* gv    = (const float*)d_in[11];
    const float* betav = (const float*)d_in[12];
    const float* Wo    = (const float*)d_in[13];
    const float* bo    = (const float*)d_in[14];
    const float* Wc    = (const float*)d_in[15];
    const float* bc    = (const float*)d_in[16];

    float* out_o    = (float*)d_out;
    float* out_c    = out_o + (size_t)S_SEQ * D_DIM;
    float* out_attn = out_c + (size_t)S_SEQ * NCLS;

    char* cur = (char*)d_ws;
    auto alloc = [&](size_t bytes) {
        char* p = cur;
        cur += (bytes + 255) & ~(size_t)255;
        return p;
    };
    const size_t SD2 = (size_t)S_SEQ * D_DIM * 2;
    const size_t DD2 = (size_t)D_DIM * D_DIM * 2;
    unsigned short* xb   = (unsigned short*)alloc(SD2);
    unsigned short* wqkv = (unsigned short*)alloc(3 * DD2);
    unsigned short* wto  = (unsigned short*)alloc(DD2);
    unsigned short* qb   = (unsigned short*)alloc(SD2);
    unsigned short* kb   = (unsigned short*)alloc(SD2);
    unsigned short* vb   = (unsigned short*)alloc(SD2);
    unsigned short* Vt   = (unsigned short*)alloc(SD2);
    unsigned short* valb = (unsigned short*)alloc(SD2);
    float* rmax   = (float*)alloc((size_t)S_SEQ * 4);
    float* rrecip = (float*)alloc((size_t)S_SEQ * 4);
    unsigned short* At = (unsigned short*)alloc((size_t)S_SEQ * S_SEQ * 2);
    unsigned short* Lb = (unsigned short*)alloc((size_t)S_SEQ * S_SEQ * 2);

    // overlays: pmax/psum (8192 x 128 fp32 each) over xb (dead after QKV GEMM)
    float* pmax = (float*)xb;
    float* psum = pmax + (size_t)S_SEQ * 128;

    const int n4_xd = S_SEQ * D_DIM / 4;

    // x -> bf16
    k_f32_to_bf16<<<n4_xd / 256, 256, 0, stream>>>(x, xb, n4_xd);
    // weight transposes: fp32 [K][N] -> bf16 [N][K]; q/k/v concatenated along N
    k_transpose_f32_bf16<<<dim3(16, 16), 256, 0, stream>>>(Wq, wqkv, D_DIM, D_DIM);
    k_transpose_f32_bf16<<<dim3(16, 16), 256, 0, stream>>>(Wk, wqkv + (size_t)D_DIM * D_DIM, D_DIM, D_DIM);
    k_transpose_f32_bf16<<<dim3(16, 16), 256, 0, stream>>>(Wv, wqkv + (size_t)2 * D_DIM * D_DIM, D_DIM, D_DIM);
    k_transpose_f32_bf16<<<dim3(16, 16), 256, 0, stream>>>(Wo, wto, D_DIM, D_DIM);
    // classifier (independent)
    k_classifier<<<S_SEQ, 256, 0, stream>>>(x, Wc, bc, out_c);

    // fused QKV GEMM: [8192][3072] fp32 into out_attn scratch (chunked mapping)
    float* qkv = out_attn;
    k_gemm_big<128, 4, 2, 3, 0><<<(S_SEQ / 256) * (3 * D_DIM / 128), 512, 0, stream>>>(
        xb, wqkv, qkv, nullptr, S_SEQ, 3 * D_DIM, D_DIM, 1.0f, nullptr, nullptr, nullptr);
    // per-chain LayerNorm -> bf16
    k_ln_bf16<<<S_SEQ, 256, 0, stream>>>(qkv,              3 * D_DIM, bq, gq, betaq, qb);
    k_ln_bf16<<<S_SEQ, 256, 0, stream>>>(qkv + D_DIM,      3 * D_DIM, bk, gk, betak, kb);
    k_ln_bf16<<<S_SEQ, 256, 0, stream>>>(qkv + 2 * D_DIM,  3 * D_DIM, bv, gv, betav, vb);

    // V^T for the A^T V GEMM
    k_transpose_bf16<<<dim3(S_SEQ / 64, D_DIM / 64), 256, 0, stream>>>(vb, Vt, S_SEQ, D_DIM);

    // logits = q k^T / 32 -> bf16 Lb, fused per-tile softmax stats
    // npx mapping: nbn=64 -> 8 bn per XCD (2 MB B L2-resident, A shared in-XCD)
    k_gemm_big<128, 4, 2, 3, 1><<<(S_SEQ / 256) * (S_SEQ / 128), 512, 0, stream>>>(
        qb, kb, nullptr, Lb, S_SEQ, S_SEQ, D_DIM, 0.03125f, nullptr, pmax, psum);

    // combine stats, then normalize -> fp32 attention output + bf16 At
    k_stats_reduce<<<S_SEQ / 4, 256, 0, stream>>>(pmax, psum, rmax, rrecip, S_SEQ / 64);
    k_norm_transpose<<<dim3(S_SEQ / 64, S_SEQ / 64), 256, 0, stream>>>(
        Lb, out_attn, rmax, rrecip, At);

    // values = A^T V -> bf16 valb (chunked mapping: A-panel reuse in-XCD)
    k_gemm_big<128, 4, 2, 3, 0><<<(S_SEQ / 256) * (D_DIM / 128), 512, 0, stream>>>(
        At, Vt, nullptr, valb, S_SEQ, D_DIM, S_SEQ, 1.0f, nullptr, nullptr, nullptr);

    // o = values @ Wo + bo
    k_gemm_big<128, 4, 2, 3, 0><<<(S_SEQ / 256) * (D_DIM / 128), 512, 0, stream>>>(
        valb, wto, out_o, nullptr, S_SEQ, D_DIM, D_DIM, 1.0f, bo, nullptr, nullptr);
}

// Round 7
// 596.656 us; speedup vs baseline: 1.2339x; 1.0393x over previous
//
#include <hip/hip_runtime.h>
#include <hip/hip_bf16.h>

#define S_SEQ 8192
#define D_DIM 1024
#define NCLS 7

typedef __bf16 bf16x8 __attribute__((ext_vector_type(8)));
typedef float f32x4 __attribute__((ext_vector_type(4)));

typedef const __attribute__((address_space(1))) void* gas_ptr;
typedef __attribute__((address_space(3))) void* las_ptr;
#define GLL(gp, lp) __builtin_amdgcn_global_load_lds((gas_ptr)(const void*)(gp), (las_ptr)(void*)(lp), 16, 0, 0)

__device__ __forceinline__ unsigned short f2bf(float f) {
    unsigned int u = __builtin_bit_cast(unsigned int, f);
    u = (u + 0x7FFFu + ((u >> 16) & 1u)) >> 16;
    return (unsigned short)u;
}
__device__ __forceinline__ float bf2f(unsigned short h) {
    unsigned int u = ((unsigned int)h) << 16;
    return __builtin_bit_cast(float, u);
}

// ---------------- elementwise fp32 -> bf16 ----------------
__global__ __launch_bounds__(256) void k_f32_to_bf16(const float* __restrict__ src,
                                                     unsigned short* __restrict__ dst, int n4) {
    int i = blockIdx.x * 256 + threadIdx.x;
    if (i >= n4) return;
    float4 v = ((const float4*)src)[i];
    ushort4 o;
    o.x = f2bf(v.x); o.y = f2bf(v.y); o.z = f2bf(v.z); o.w = f2bf(v.w);
    ((ushort4*)dst)[i] = o;
}

// ---------------- sum of two fp32 arrays -> bf16 ----------------
__global__ __launch_bounds__(256) void k_sum2_bf16(const float* __restrict__ a,
                                                   const float* __restrict__ b,
                                                   unsigned short* __restrict__ dst, int n4) {
    int i = blockIdx.x * 256 + threadIdx.x;
    if (i >= n4) return;
    float4 va = ((const float4*)a)[i];
    float4 vb = ((const float4*)b)[i];
    ushort4 o;
    o.x = f2bf(va.x + vb.x); o.y = f2bf(va.y + vb.y);
    o.z = f2bf(va.z + vb.z); o.w = f2bf(va.w + vb.w);
    ((ushort4*)dst)[i] = o;
}

// ---------------- transpose fp32 [R][C] -> bf16 [C][R] ----------------
__global__ __launch_bounds__(256) void k_transpose_f32_bf16(const float* __restrict__ src,
                                                            unsigned short* __restrict__ dst,
                                                            int R, int C) {
    __shared__ unsigned short t[64][80];
    int r0 = blockIdx.x * 64, c0 = blockIdx.y * 64;
    int tid = threadIdx.x;
    int rr = tid >> 4, cc = (tid & 15) << 2;
#pragma unroll
    for (int p = 0; p < 4; ++p) {
        int r = rr + p * 16;
        float4 v = *(const float4*)(src + (size_t)(r0 + r) * C + c0 + cc);
        t[cc + 0][r] = f2bf(v.x);
        t[cc + 1][r] = f2bf(v.y);
        t[cc + 2][r] = f2bf(v.z);
        t[cc + 3][r] = f2bf(v.w);
    }
    __syncthreads();
    int wr = tid >> 3, wc = (tid & 7) << 3;
#pragma unroll
    for (int p = 0; p < 2; ++p) {
        int c = wr + p * 32;
        uint4 v8 = *(const uint4*)&t[c][wc];
        *(uint4*)(dst + (size_t)(c0 + c) * R + r0 + wc) = v8;
    }
}

// ---------------- transpose bf16 [R][C] -> bf16 [C][R] ----------------
__global__ __launch_bounds__(256) void k_transpose_bf16(const unsigned short* __restrict__ src,
                                                        unsigned short* __restrict__ dst,
                                                        int R, int C) {
    __shared__ unsigned short t[64][80];
    int r0 = blockIdx.x * 64, c0 = blockIdx.y * 64;
    int tid = threadIdx.x;
    int rr = tid >> 3, cc = (tid & 7) << 3;
#pragma unroll
    for (int p = 0; p < 2; ++p) {
        int r = rr + p * 32;
        uint4 v = *(const uint4*)(src + (size_t)(r0 + r) * C + c0 + cc);
        const unsigned short* pv = (const unsigned short*)&v;
#pragma unroll
        for (int i = 0; i < 8; ++i) t[cc + i][r] = pv[i];
    }
    __syncthreads();
    int wr = tid >> 3, wc = (tid & 7) << 3;
#pragma unroll
    for (int p = 0; p < 2; ++p) {
        int c = wr + p * 32;
        uint4 v8 = *(const uint4*)&t[c][wc];
        *(uint4*)(dst + (size_t)(c0 + c) * R + r0 + wc) = v8;
    }
}

// ---------------- LayerNorm row kernel (strided input): bf16 out ----------------
__global__ __launch_bounds__(256) void k_ln_bf16(const float* __restrict__ Y, int ldy,
                                                 const float* __restrict__ bias,
                                                 const float* __restrict__ g,
                                                 const float* __restrict__ beta,
                                                 unsigned short* __restrict__ out) {
    __shared__ float red[8];
    int row = blockIdx.x, tid = threadIdx.x;
    float4 y = *(const float4*)(Y + (size_t)row * ldy + tid * 4);
    float4 b4 = *(const float4*)(bias + tid * 4);
    y.x += b4.x; y.y += b4.y; y.z += b4.z; y.w += b4.w;
    float s = y.x + y.y + y.z + y.w;
    float s2 = y.x * y.x + y.y * y.y + y.z * y.z + y.w * y.w;
#pragma unroll
    for (int o = 32; o; o >>= 1) { s += __shfl_down(s, o); s2 += __shfl_down(s2, o); }
    int lane = tid & 63, wv = tid >> 6;
    if (lane == 0) { red[wv] = s; red[4 + wv] = s2; }
    __syncthreads();
    s = red[0] + red[1] + red[2] + red[3];
    s2 = red[4] + red[5] + red[6] + red[7];
    float m = s * (1.0f / D_DIM);
    float var = s2 * (1.0f / D_DIM) - m * m;
    float rs = rsqrtf(var + 1e-5f);
    float4 g4 = *(const float4*)(g + tid * 4);
    float4 be4 = *(const float4*)(beta + tid * 4);
    ushort4 o4;
    o4.x = f2bf((y.x - m) * rs * g4.x + be4.x);
    o4.y = f2bf((y.y - m) * rs * g4.y + be4.y);
    o4.z = f2bf((y.z - m) * rs * g4.z + be4.z);
    o4.w = f2bf((y.w - m) * rs * g4.w + be4.w);
    *(ushort4*)(out + (size_t)row * D_DIM + tid * 4) = o4;
}

// ---------------- combine per-tile stats: rmax, rrecip ----------------
__global__ __launch_bounds__(256) void k_stats_reduce(const float* __restrict__ pmax,
                                                      const float* __restrict__ psum,
                                                      float* __restrict__ rmax,
                                                      float* __restrict__ rrecip, int nblk) {
    int row = blockIdx.x * 4 + (threadIdx.x >> 6);
    int lane = threadIdx.x & 63;
    const float* pm = pmax + (size_t)row * nblk;
    const float* ps = psum + (size_t)row * nblk;
    float m = -3.4e38f;
    for (int j = lane; j < nblk; j += 64) m = fmaxf(m, pm[j]);
#pragma unroll
    for (int mk = 32; mk; mk >>= 1) m = fmaxf(m, __shfl_xor(m, mk));
    float s = 0.0f;
    for (int j = lane; j < nblk; j += 64) s += ps[j] * __expf(pm[j] - m);
#pragma unroll
    for (int mk = 32; mk; mk >>= 1) s += __shfl_xor(s, mk);
    if (lane == 0) { rmax[row] = m; rrecip[row] = 1.0f / s; }
}

// ------- normalize: bf16 logits -> fp32 attn + bf16 At -------
__global__ __launch_bounds__(256) void k_norm_transpose(const unsigned short* __restrict__ src16,
                                                        float* __restrict__ attn,
                                                        const float* __restrict__ rmax,
                                                        const float* __restrict__ rrecip,
                                                        unsigned short* __restrict__ At) {
    __shared__ unsigned short t[64][80];
    int t0 = blockIdx.x * 64, s0 = blockIdx.y * 64;
    int tid = threadIdx.x;
    int rr = tid >> 4, cc = (tid & 15) << 2;
#pragma unroll
    for (int p = 0; p < 4; ++p) {
        int r = rr + p * 16;
        float m = rmax[t0 + r], rc = rrecip[t0 + r];
        size_t off = (size_t)(t0 + r) * S_SEQ + s0 + cc;
        ushort4 u = *(const ushort4*)(src16 + off);
        float4 v;
        v.x = __expf(bf2f(u.x) - m) * rc;
        v.y = __expf(bf2f(u.y) - m) * rc;
        v.z = __expf(bf2f(u.z) - m) * rc;
        v.w = __expf(bf2f(u.w) - m) * rc;
        *(float4*)(attn + off) = v;
        t[cc + 0][r] = f2bf(v.x);
        t[cc + 1][r] = f2bf(v.y);
        t[cc + 2][r] = f2bf(v.z);
        t[cc + 3][r] = f2bf(v.w);
    }
    __syncthreads();
    int wr = tid >> 3, wc = (tid & 7) << 3;
#pragma unroll
    for (int p = 0; p < 2; ++p) {
        int c = wr + p * 32;
        uint4 v8 = *(const uint4*)&t[c][wc];
        *(uint4*)(At + (size_t)(s0 + c) * S_SEQ + t0 + wc) = v8;
    }
}

// ---------------- classifier: c = x @ Wc + bc ----------------
__global__ __launch_bounds__(256) void k_classifier(const float* __restrict__ x,
                                                    const float* __restrict__ Wc,
                                                    const float* __restrict__ bc,
                                                    float* __restrict__ outc) {
    __shared__ float red[4][NCLS];
    int row = blockIdx.x, tid = threadIdx.x;
    float4 xv = *(const float4*)(x + (size_t)row * D_DIM + tid * 4);
    const float* w0 = Wc + (size_t)(tid * 4) * NCLS;
    float acc[NCLS];
#pragma unroll
    for (int j = 0; j < NCLS; ++j)
        acc[j] = xv.x * w0[j] + xv.y * w0[NCLS + j] + xv.z * w0[2 * NCLS + j] + xv.w * w0[3 * NCLS + j];
#pragma unroll
    for (int j = 0; j < NCLS; ++j)
#pragma unroll
        for (int o = 32; o; o >>= 1) acc[j] += __shfl_down(acc[j], o);
    int lane = tid & 63, wv = tid >> 6;
    if (lane == 0) {
#pragma unroll
        for (int j = 0; j < NCLS; ++j) red[wv][j] = acc[j];
    }
    __syncthreads();
    if (tid < NCLS) {
        float s = red[0][tid] + red[1][tid] + red[2][tid] + red[3][tid];
        outc[(size_t)row * NCLS + tid] = s + bc[tid];
    }
}

// ======== 8-phase 256x256 bf16 GEMM: C[M,N] = scale*A[M,K]*B[N,K]^T (+bias) ========
// BK=64, 2 K-tiles/iter, 8 waves (2M x 4N), per-wave 128x64 output, 128 KiB LDS
// [dbuf][A/B][half][128x64], per-phase {ds_read subtile || 1 half-tile GLL stage ->
// barrier -> lgkmcnt(0) -> setprio(1) 16 MFMA setprio(0) -> barrier}, counted
// vmcnt(4) at phases 4 and 8 only. XOR swizzle (elem ^= (row&7)<<3) applied via
// inverse-swizzled global source. Requires M%256==0, N%256==0, K%(128*SK)==0, K/SK>=256.
template<int SK, int USE_NPX>
__global__ __launch_bounds__(512) void k_gemm_8ph(const unsigned short* __restrict__ A,
                                                  const unsigned short* __restrict__ B,
                                                  float* __restrict__ C0,
                                                  float* __restrict__ C1,
                                                  unsigned short* __restrict__ Cb,
                                                  int M, int N, int K, float scale,
                                                  const float* __restrict__ bias,
                                                  float* __restrict__ pmax,
                                                  float* __restrict__ psum) {
    __shared__ unsigned short lds[2][2][2][8192];   // [dbuf][A=0/B=1][half][row*64+col]

    const int tid = threadIdx.x;
    const int lane = tid & 63;
    const int wid = tid >> 6;
    const int wm = wid >> 2;          // 0..1
    const int wn = wid & 3;           // 0..3
    const int fm = lane & 15;
    const int g = lane >> 4;

    const int nbm = M >> 8;
    const int nbn = N >> 8;
    int bm, bn, sk;
    if (USE_NPX && ((nbn & 7) == 0) && ((gridDim.x & 7) == 0)) {
        const int npx = nbn >> 3;
        const int xcd = blockIdx.x & 7;
        const int c = blockIdx.x >> 3;
        bn = xcd * npx + (c % npx);
        const int r2 = c / npx;
        bm = r2 % nbm;
        sk = r2 / nbm;
    } else if ((gridDim.x & 7) == 0) {
        int wg = (blockIdx.x & 7) * (gridDim.x >> 3) + (blockIdx.x >> 3);
        sk = wg / (nbm * nbn);
        int rem = wg % (nbm * nbn);
        bm = rem / nbn;
        bn = rem % nbn;
    } else {
        bm = blockIdx.x / nbn; bn = blockIdx.x % nbn; sk = 0;
    }
    const int brow = bm << 8;
    const int bcol = bn << 8;
    const int Ksub = K / SK;
    const int koff = sk * Ksub;
    const int NKT = Ksub >> 6;       // K-tiles of 64
    const int NI = NKT >> 1;         // iters (2 K-tiles each)
    float* __restrict__ C = (SK == 2 && sk == 1) ? C1 : C0;

    // ---- staging: inverse-swizzled global source, linear LDS dest ----
    const int srow = tid >> 3;                               // 0..63
    const int scol = ((tid & 7) << 3) ^ ((srow & 7) << 3);   // element col in 64-wide row

    auto stA = [&](int kt, int h) {
        const unsigned short* s = A + (size_t)(brow + h * 128 + srow) * K + koff + kt * 64 + scol;
        unsigned short* d = &lds[kt & 1][0][h][tid * 8];
        GLL(s, d);
        GLL(s + (size_t)64 * K, d + 4096);
    };
    auto stB = [&](int kt, int h) {
        const unsigned short* s = B + (size_t)(bcol + h * 128 + srow) * K + koff + kt * 64 + scol;
        unsigned short* d = &lds[kt & 1][1][h][tid * 8];
        GLL(s, d);
        GLL(s + (size_t)64 * K, d + 4096);
    };

    f32x4 acc[8][4] = {};
    bf16x8 breg[4][2];

    // swizzled fragment read: row-local within half, kcol = ks*32 + g*8
#define LD_A(db, q, ii, ks) \
    (*(const bf16x8*)&lds[db][0][wm][((q)*32 + (ii)*16 + fm) * 64 + ((((ks)*32 + g*8)) ^ ((((q)*32 + (ii)*16 + fm) & 7) << 3))])
#define LD_B(db, j, ks) \
    (*(const bf16x8*)&lds[db][1][wn >> 1][((wn & 1)*64 + (j)*16 + fm) * 64 + ((((ks)*32 + g*8)) ^ (((((wn & 1)*64 + (j)*16 + fm)) & 7) << 3))])

#define MFMA16(q, a00, a10, a01, a11)                                                          \
    {                                                                                          \
        __builtin_amdgcn_s_setprio(1);                                                         \
        _Pragma("unroll")                                                                      \
        for (int j = 0; j < 4; ++j) {                                                          \
            acc[(q)*2 + 0][j] = __builtin_amdgcn_mfma_f32_16x16x32_bf16(a00, breg[j][0], acc[(q)*2 + 0][j], 0, 0, 0); \
            acc[(q)*2 + 1][j] = __builtin_amdgcn_mfma_f32_16x16x32_bf16(a10, breg[j][0], acc[(q)*2 + 1][j], 0, 0, 0); \
            acc[(q)*2 + 0][j] = __builtin_amdgcn_mfma_f32_16x16x32_bf16(a01, breg[j][1], acc[(q)*2 + 0][j], 0, 0, 0); \
            acc[(q)*2 + 1][j] = __builtin_amdgcn_mfma_f32_16x16x32_bf16(a11, breg[j][1], acc[(q)*2 + 1][j], 0, 0, 0); \
        }                                                                                      \
        __builtin_amdgcn_s_setprio(0);                                                         \
    }

#define BAR()  __builtin_amdgcn_s_barrier()
#define LGKM0() asm volatile("s_waitcnt lgkmcnt(0)" ::: "memory")
#define VM(n)  asm volatile("s_waitcnt vmcnt(%0)" :: "n"(n) : "memory")

    // ---- prologue: tile0 (B,A) + tile1 (B); tile1.A staged in iter0 p1/p2 ----
    stB(0, 0); stB(0, 1);
    stA(0, 0); stA(0, 1);
    stB(1, 0); stB(1, 1);
    VM(4);                       // tile0 fully resident; tile1.B outstanding
    BAR();

    for (int it = 0; it < NI; ++it) {
        const int kt1 = 2 * it + 1;
        const bool pfA = (2 * it + 2) < NKT;   // tile kt0+2 valid (A' and B')
        const bool pfB = (2 * it + 3) < NKT;   // tile kt1+2 valid (B'')

        // ======== phase 1 (dbuf0, q0) ========
        {
            bf16x8 a00 = LD_A(0, 0, 0, 0), a10 = LD_A(0, 0, 1, 0);
            bf16x8 a01 = LD_A(0, 0, 0, 1), a11 = LD_A(0, 0, 1, 1);
#pragma unroll
            for (int j = 0; j < 4; ++j) { breg[j][0] = LD_B(0, j, 0); breg[j][1] = LD_B(0, j, 1); }
            stA(kt1, 0);                                   // tile(2t+1).A-h0 -> dbuf1.A
            BAR(); LGKM0();
            MFMA16(0, a00, a10, a01, a11);
            BAR();
        }
        // ======== phase 2 (dbuf0, q1) ========
        {
            bf16x8 a00 = LD_A(0, 1, 0, 0), a10 = LD_A(0, 1, 1, 0);
            bf16x8 a01 = LD_A(0, 1, 0, 1), a11 = LD_A(0, 1, 1, 1);
            stA(kt1, 1);                                   // tile(2t+1).A-h1
            if (pfA) stB(2 * it + 2, 0);                   // tile(2t+2).B-h0 -> dbuf0.B
            BAR(); LGKM0();
            MFMA16(1, a00, a10, a01, a11);
            BAR();
        }
        // ======== phase 3 (dbuf0, q2) ========
        {
            bf16x8 a00 = LD_A(0, 2, 0, 0), a10 = LD_A(0, 2, 1, 0);
            bf16x8 a01 = LD_A(0, 2, 0, 1), a11 = LD_A(0, 2, 1, 1);
            if (pfA) stB(2 * it + 2, 1);                   // tile(2t+2).B-h1
            BAR(); LGKM0();
            MFMA16(2, a00, a10, a01, a11);
            BAR();
        }
        // ======== phase 4 (dbuf0, q3) + vmcnt ========
        {
            bf16x8 a00 = LD_A(0, 3, 0, 0), a10 = LD_A(0, 3, 1, 0);
            bf16x8 a01 = LD_A(0, 3, 0, 1), a11 = LD_A(0, 3, 1, 1);
            BAR(); LGKM0();
            MFMA16(3, a00, a10, a01, a11);
            if (pfA) { VM(4); } else { VM(0); }            // dbuf1 (tile 2t+1) resident
            BAR();
        }
        // ======== phase 5 (dbuf1, q0) ========
        {
            bf16x8 a00 = LD_A(1, 0, 0, 0), a10 = LD_A(1, 0, 1, 0);
            bf16x8 a01 = LD_A(1, 0, 0, 1), a11 = LD_A(1, 0, 1, 1);
#pragma unroll
            for (int j = 0; j < 4; ++j) { breg[j][0] = LD_B(1, j, 0); breg[j][1] = LD_B(1, j, 1); }
            if (pfA) stA(2 * it + 2, 0);                   // tile(2t+2).A-h0 -> dbuf0.A
            BAR(); LGKM0();
            MFMA16(0, a00, a10, a01, a11);
            BAR();
        }
        // ======== phase 6 (dbuf1, q1) ========
        {
            bf16x8 a00 = LD_A(1, 1, 0, 0), a10 = LD_A(1, 1, 1, 0);
            bf16x8 a01 = LD_A(1, 1, 0, 1), a11 = LD_A(1, 1, 1, 1);
            if (pfA) stA(2 * it + 2, 1);                   // tile(2t+2).A-h1
            if (pfB) stB(2 * it + 3, 0);                   // tile(2t+3).B-h0 -> dbuf1.B
            BAR(); LGKM0();
            MFMA16(1, a00, a10, a01, a11);
            BAR();
        }
        // ======== phase 7 (dbuf1, q2) ========
        {
            bf16x8 a00 = LD_A(1, 2, 0, 0), a10 = LD_A(1, 2, 1, 0);
            bf16x8 a01 = LD_A(1, 2, 0, 1), a11 = LD_A(1, 2, 1, 1);
            if (pfB) stB(2 * it + 3, 1);                   // tile(2t+3).B-h1
            BAR(); LGKM0();
            MFMA16(2, a00, a10, a01, a11);
            BAR();
        }
        // ======== phase 8 (dbuf1, q3) + vmcnt ========
        {
            bf16x8 a00 = LD_A(1, 3, 0, 0), a10 = LD_A(1, 3, 1, 0);
            bf16x8 a01 = LD_A(1, 3, 0, 1), a11 = LD_A(1, 3, 1, 1);
            BAR(); LGKM0();
            MFMA16(3, a00, a10, a01, a11);
            if (it + 1 < NI) {
                if (pfB) { VM(4); } else { VM(0); }        // next iter's dbuf0 resident
            }
            BAR();
        }
    }

    // ---- fused softmax-stat epilogue ----
    if (psum) {
        const int nblk = N >> 6;
        const int cblk = (bcol >> 6) + wn;
#pragma unroll
        for (int i = 0; i < 8; ++i) {
#pragma unroll
            for (int r = 0; r < 4; ++r) {
                float v0 = acc[i][0][r] * scale, v1 = acc[i][1][r] * scale;
                float v2 = acc[i][2][r] * scale, v3 = acc[i][3][r] * scale;
                float mv = fmaxf(fmaxf(v0, v1), fmaxf(v2, v3));
#pragma unroll
                for (int mk = 1; mk < 16; mk <<= 1) mv = fmaxf(mv, __shfl_xor(mv, mk));
                float sv = __expf(v0 - mv) + __expf(v1 - mv) + __expf(v2 - mv) + __expf(v3 - mv);
#pragma unroll
                for (int mk = 1; mk < 16; mk <<= 1) sv += __shfl_xor(sv, mk);
                if (fm == 0) {
                    int row = brow + wm * 128 + i * 16 + (g << 2) + r;
                    pmax[(size_t)row * nblk + cblk] = mv;
                    psum[(size_t)row * nblk + cblk] = sv;
                }
            }
        }
    }

    // ---- store ----
    if (Cb) {
#pragma unroll
        for (int i = 0; i < 8; ++i) {
#pragma unroll
            for (int j = 0; j < 4; ++j) {
                int col = bcol + wn * 64 + j * 16 + fm;
#pragma unroll
                for (int r = 0; r < 4; ++r) {
                    int row = brow + wm * 128 + i * 16 + (g << 2) + r;
                    Cb[(size_t)row * N + col] = f2bf(acc[i][j][r] * scale);
                }
            }
        }
    } else {
#pragma unroll
        for (int i = 0; i < 8; ++i) {
#pragma unroll
            for (int j = 0; j < 4; ++j) {
                int col = bcol + wn * 64 + j * 16 + fm;
                float badd = bias ? bias[col] : 0.0f;
#pragma unroll
                for (int r = 0; r < 4; ++r) {
                    int row = brow + wm * 128 + i * 16 + (g << 2) + r;
                    C[(size_t)row * N + col] = acc[i][j][r] * scale + badd;
                }
            }
        }
    }
#undef LD_A
#undef LD_B
#undef MFMA16
#undef BAR
#undef LGKM0
#undef VM
}

// ============ pipelined bf16 GEMM (old structure, kept for o-GEMM) ============
template<int BN, int WM, int WN, int NSLOT, int USE_NPX>
__global__ __launch_bounds__(512) void k_gemm_big(const unsigned short* __restrict__ A,
                                                  const unsigned short* __restrict__ B,
                                                  float* __restrict__ C,
                                                  unsigned short* __restrict__ Cb,
                                                  int M, int N, int K,
                                                  float scale,
                                                  const float* __restrict__ bias) {
    constexpr int MREP = 256 / WM / 16;
    constexpr int NREP = BN / WN / 16;
    constexpr int PHASES = MREP / 4;
    constexpr int BISS = BN / 128;
    constexpr int TISS = 2 + BISS;
    constexpr int DEPTH = NSLOT - 1;
    constexpr int ASLOT = 256 * 32;
    constexpr int BSLOT = BN * 32;
    constexpr int SLOT = ASLOT + BSLOT;
    __shared__ unsigned short lds[NSLOT * SLOT];

    const int tid = threadIdx.x;
    const int lane = tid & 63;
    const int wid = tid >> 6;
    const int wm = wid / WN;
    const int wn = wid % WN;
    const int fm = lane & 15;
    const int g = lane >> 4;

    const int nbn = N / BN;
    int bm, bn;
    if ((gridDim.x & 7) == 0) {
        int wg = (blockIdx.x & 7) * (gridDim.x >> 3) + (blockIdx.x >> 3);
        bm = wg / nbn; bn = wg % nbn;
    } else {
        bm = blockIdx.x / nbn; bn = blockIdx.x % nbn;
    }
    const int brow = bm << 8;
    const int bcol = bn * BN;
    const int NT = K >> 5;

    const int arow = tid >> 2;
    const int scb = ((tid & 3) << 4) ^ ((arow & 6) << 3);
    const unsigned short* gA = A + (size_t)(brow + arow) * K + (scb >> 1);
    const unsigned short* gB = B + (size_t)(bcol + arow) * K + (scb >> 1);
    unsigned short* lA = lds + tid * 8;
    unsigned short* lB = lds + ASLOT + tid * 8;
    const size_t rows128 = (size_t)128 * K;

    auto stageA = [&](int kt, int slot) {
        const unsigned short* s = gA + ((size_t)kt << 5);
        unsigned short* d = lA + slot * SLOT;
        GLL(s, d);
        GLL(s + rows128, d + 4096);
    };
    auto stageB = [&](int kt, int slot) {
        const unsigned short* s = gB + ((size_t)kt << 5);
        unsigned short* d = lB + slot * SLOT;
#pragma unroll
        for (int h = 0; h < BISS; ++h)
            GLL(s + (size_t)h * rows128, d + h * 4096);
    };

    const int cbf = (((g << 4) ^ ((fm & 6) << 3)) >> 1);
    const unsigned short* fA = lds + (wm * (256 / WM) + fm) * 32 + cbf;
    const unsigned short* fB = lds + ASLOT + (wn * (BN / WN) + fm) * 32 + cbf;

    f32x4 acc[MREP][NREP] = {};

#pragma unroll
    for (int p = 0; p < DEPTH; ++p) { stageA(p, p); stageB(p, p); }
    asm volatile("s_waitcnt vmcnt(%0)" :: "n"((DEPTH - 1) * TISS) : "memory");
    __builtin_amdgcn_s_barrier();

    for (int t = 0; t < NT; ++t) {
        const int slot = t % NSLOT;
        const unsigned short* sA = fA + slot * SLOT;
        const unsigned short* sB = fB + slot * SLOT;
        const int pslot = (t + DEPTH) % NSLOT;
        const bool pf = (t + DEPTH) < NT;

        bf16x8 bfr[NREP];
        bf16x8 afr[4];
#pragma unroll
        for (int i = 0; i < 4; ++i) afr[i] = *(const bf16x8*)(sA + i * 512);
#pragma unroll
        for (int j = 0; j < NREP; ++j) bfr[j] = *(const bf16x8*)(sB + j * 512);
        if (pf) {
            stageA(t + DEPTH, pslot);
            if (PHASES == 1) stageB(t + DEPTH, pslot);
        }
        __builtin_amdgcn_s_barrier();
        asm volatile("s_waitcnt lgkmcnt(0)" ::: "memory");
        __builtin_amdgcn_s_setprio(1);
#pragma unroll
        for (int i = 0; i < 4; ++i)
#pragma unroll
            for (int j = 0; j < NREP; ++j)
                acc[i][j] = __builtin_amdgcn_mfma_f32_16x16x32_bf16(afr[i], bfr[j], acc[i][j], 0, 0, 0);
        __builtin_amdgcn_s_setprio(0);
        __builtin_amdgcn_s_barrier();

        if (PHASES == 2) {
#pragma unroll
            for (int i = 0; i < 4; ++i) afr[i] = *(const bf16x8*)(sA + (i + 4) * 512);
            if (pf) stageB(t + DEPTH, pslot);
            __builtin_amdgcn_s_barrier();
            asm volatile("s_waitcnt lgkmcnt(0)" ::: "memory");
            __builtin_amdgcn_s_setprio(1);
#pragma unroll
            for (int i = 0; i < 4; ++i)
#pragma unroll
                for (int j = 0; j < NREP; ++j)
                    acc[(i + 4) % MREP][j] = __builtin_amdgcn_mfma_f32_16x16x32_bf16(afr[i], bfr[j], acc[(i + 4) % MREP][j], 0, 0, 0);
            __builtin_amdgcn_s_setprio(0);
        }

        if (t + 1 < NT) {
            if (t + DEPTH < NT)
                asm volatile("s_waitcnt vmcnt(%0)" :: "n"(TISS) : "memory");
            else
                asm volatile("s_waitcnt vmcnt(0)" ::: "memory");
        }
        __builtin_amdgcn_s_barrier();
    }

    const int r0 = g << 2;
    if (Cb) {
#pragma unroll
        for (int i = 0; i < MREP; ++i)
#pragma unroll
            for (int j = 0; j < NREP; ++j) {
                int col = bcol + wn * (BN / WN) + j * 16 + fm;
#pragma unroll
                for (int r = 0; r < 4; ++r) {
                    int row = brow + wm * (256 / WM) + i * 16 + r0 + r;
                    Cb[(size_t)row * N + col] = f2bf(acc[i][j][r] * scale);
                }
            }
    } else {
#pragma unroll
        for (int i = 0; i < MREP; ++i)
#pragma unroll
            for (int j = 0; j < NREP; ++j) {
                int col = bcol + wn * (BN / WN) + j * 16 + fm;
                float badd = bias ? bias[col] : 0.0f;
#pragma unroll
                for (int r = 0; r < 4; ++r) {
                    int row = brow + wm * (256 / WM) + i * 16 + r0 + r;
                    C[(size_t)row * N + col] = acc[i][j][r] * scale + badd;
                }
            }
    }
}

extern "C" void kernel_launch(void* const* d_in, const int* in_sizes, int n_in,
                              void* d_out, int out_size, void* d_ws, size_t ws_size,
                              hipStream_t stream) {
    const float* x     = (const float*)d_in[0];
    const float* Wq    = (const float*)d_in[1];
    const float* bq    = (const float*)d_in[2];
    const float* gq    = (const float*)d_in[3];
    const float* betaq = (const float*)d_in[4];
    const float* Wk    = (const float*)d_in[5];
    const float* bk    = (const float*)d_in[6];
    const float* gk    = (const float*)d_in[7];
    const float* betak = (const float*)d_in[8];
    const float* Wv    = (const float*)d_in[9];
    const float* bv    = (const float*)d_in[10];
    const float* gv    = (const float*)d_in[11];
    const float* betav = (const float*)d_in[12];
    const float* Wo    = (const float*)d_in[13];
    const float* bo    = (const float*)d_in[14];
    const float* Wc    = (const float*)d_in[15];
    const float* bc    = (const float*)d_in[16];

    float* out_o    = (float*)d_out;
    float* out_c    = out_o + (size_t)S_SEQ * D_DIM;
    float* out_attn = out_c + (size_t)S_SEQ * NCLS;

    char* cur = (char*)d_ws;
    auto alloc = [&](size_t bytes) {
        char* p = cur;
        cur += (bytes + 255) & ~(size_t)255;
        return p;
    };
    const size_t SD2 = (size_t)S_SEQ * D_DIM * 2;
    const size_t DD2 = (size_t)D_DIM * D_DIM * 2;
    unsigned short* xb   = (unsigned short*)alloc(SD2);
    unsigned short* wqkv = (unsigned short*)alloc(3 * DD2);
    unsigned short* wto  = (unsigned short*)alloc(DD2);
    unsigned short* qb   = (unsigned short*)alloc(SD2);
    unsigned short* kb   = (unsigned short*)alloc(SD2);
    unsigned short* vb   = (unsigned short*)alloc(SD2);
    unsigned short* Vt   = (unsigned short*)alloc(SD2);
    unsigned short* valb = (unsigned short*)alloc(SD2);
    float* rmax   = (float*)alloc((size_t)S_SEQ * 4);
    float* rrecip = (float*)alloc((size_t)S_SEQ * 4);
    unsigned short* At = (unsigned short*)alloc((size_t)S_SEQ * S_SEQ * 2);
    unsigned short* Lb = (unsigned short*)alloc((size_t)S_SEQ * S_SEQ * 2);

    // overlays: pmax/psum over xb (dead after QKV GEMM); split-K partial over qb+kb
    // (dead after QK^T; 8192*1024 fp32 = 32 MB = qb+kb exactly).
    float* pmax = (float*)xb;
    float* psum = pmax + (size_t)S_SEQ * 128;
    float* part1 = (float*)qb;

    const int n4_xd = S_SEQ * D_DIM / 4;

    // x -> bf16
    k_f32_to_bf16<<<n4_xd / 256, 256, 0, stream>>>(x, xb, n4_xd);
    // weight transposes: fp32 [K][N] -> bf16 [N][K]; q/k/v concatenated along N
    k_transpose_f32_bf16<<<dim3(16, 16), 256, 0, stream>>>(Wq, wqkv, D_DIM, D_DIM);
    k_transpose_f32_bf16<<<dim3(16, 16), 256, 0, stream>>>(Wk, wqkv + (size_t)D_DIM * D_DIM, D_DIM, D_DIM);
    k_transpose_f32_bf16<<<dim3(16, 16), 256, 0, stream>>>(Wv, wqkv + (size_t)2 * D_DIM * D_DIM, D_DIM, D_DIM);
    k_transpose_f32_bf16<<<dim3(16, 16), 256, 0, stream>>>(Wo, wto, D_DIM, D_DIM);
    // classifier (independent)
    k_classifier<<<S_SEQ, 256, 0, stream>>>(x, Wc, bc, out_c);

    // fused QKV GEMM (8-phase): [8192][3072] fp32 into out_attn scratch
    float* qkv = out_attn;
    k_gemm_8ph<1, 0><<<(S_SEQ / 256) * (3 * D_DIM / 256), 512, 0, stream>>>(
        xb, wqkv, qkv, nullptr, nullptr, S_SEQ, 3 * D_DIM, D_DIM, 1.0f, nullptr, nullptr, nullptr);
    // per-chain LayerNorm -> bf16
    k_ln_bf16<<<S_SEQ, 256, 0, stream>>>(qkv,              3 * D_DIM, bq, gq, betaq, qb);
    k_ln_bf16<<<S_SEQ, 256, 0, stream>>>(qkv + D_DIM,      3 * D_DIM, bk, gk, betak, kb);
    k_ln_bf16<<<S_SEQ, 256, 0, stream>>>(qkv + 2 * D_DIM,  3 * D_DIM, bv, gv, betav, vb);

    // V^T for the A^T V GEMM
    k_transpose_bf16<<<dim3(S_SEQ / 64, D_DIM / 64), 256, 0, stream>>>(vb, Vt, S_SEQ, D_DIM);

    // logits = q k^T / 32 -> bf16 Lb (8-phase, npx mapping), fused softmax stats
    k_gemm_8ph<1, 1><<<(S_SEQ / 256) * (S_SEQ / 256), 512, 0, stream>>>(
        qb, kb, nullptr, nullptr, Lb, S_SEQ, S_SEQ, D_DIM, 0.03125f, nullptr, pmax, psum);

    // combine stats, then normalize -> fp32 attention output + bf16 At
    k_stats_reduce<<<S_SEQ / 4, 256, 0, stream>>>(pmax, psum, rmax, rrecip, S_SEQ / 64);
    k_norm_transpose<<<dim3(S_SEQ / 64, S_SEQ / 64), 256, 0, stream>>>(
        Lb, out_attn, rmax, rrecip, At);

    // values = A^T V (8-phase, split-K=2: sk0 -> out_o scratch, sk1 -> part1), sum -> bf16
    k_gemm_8ph<2, 0><<<2 * (S_SEQ / 256) * (D_DIM / 256), 512, 0, stream>>>(
        At, Vt, out_o, part1, nullptr, S_SEQ, D_DIM, S_SEQ, 1.0f, nullptr, nullptr, nullptr);
    k_sum2_bf16<<<n4_xd / 256, 256, 0, stream>>>(out_o, part1, valb, n4_xd);

    // o = values @ Wo + bo (old structure)
    k_gemm_big<128, 4, 2, 3, 0><<<(S_SEQ / 256) * (D_DIM / 128), 512, 0, stream>>>(
        valb, wto, out_o, nullptr, S_SEQ, D_DIM, D_DIM, 1.0f, bo);
}

// Round 8
// 557.237 us; speedup vs baseline: 1.3212x; 1.0707x over previous
//
#include <hip/hip_runtime.h>
#include <hip/hip_bf16.h>

#define S_SEQ 8192
#define D_DIM 1024
#define NCLS 7

typedef __bf16 bf16x8 __attribute__((ext_vector_type(8)));
typedef float f32x4 __attribute__((ext_vector_type(4)));

typedef const __attribute__((address_space(1))) void* gas_ptr;
typedef __attribute__((address_space(3))) void* las_ptr;
#define GLL(gp, lp) __builtin_amdgcn_global_load_lds((gas_ptr)(const void*)(gp), (las_ptr)(void*)(lp), 16, 0, 0)

__device__ __forceinline__ unsigned short f2bf(float f) {
    unsigned int u = __builtin_bit_cast(unsigned int, f);
    u = (u + 0x7FFFu + ((u >> 16) & 1u)) >> 16;
    return (unsigned short)u;
}
__device__ __forceinline__ float bf2f(unsigned short h) {
    unsigned int u = ((unsigned int)h) << 16;
    return __builtin_bit_cast(float, u);
}

// ---------------- elementwise fp32 -> bf16 ----------------
__global__ __launch_bounds__(256) void k_f32_to_bf16(const float* __restrict__ src,
                                                     unsigned short* __restrict__ dst, int n4) {
    int i = blockIdx.x * 256 + threadIdx.x;
    if (i >= n4) return;
    float4 v = ((const float4*)src)[i];
    ushort4 o;
    o.x = f2bf(v.x); o.y = f2bf(v.y); o.z = f2bf(v.z); o.w = f2bf(v.w);
    ((ushort4*)dst)[i] = o;
}

// ---------------- sum of two fp32 arrays -> bf16 ----------------
__global__ __launch_bounds__(256) void k_sum2_bf16(const float* __restrict__ a,
                                                   const float* __restrict__ b,
                                                   unsigned short* __restrict__ dst, int n4) {
    int i = blockIdx.x * 256 + threadIdx.x;
    if (i >= n4) return;
    float4 va = ((const float4*)a)[i];
    float4 vb = ((const float4*)b)[i];
    ushort4 o;
    o.x = f2bf(va.x + vb.x); o.y = f2bf(va.y + vb.y);
    o.z = f2bf(va.z + vb.z); o.w = f2bf(va.w + vb.w);
    ((ushort4*)dst)[i] = o;
}

// ---------------- concat 3 bias vectors [1024] -> [3072] ----------------
__global__ __launch_bounds__(256) void k_concat3(const float* __restrict__ a,
                                                 const float* __restrict__ b,
                                                 const float* __restrict__ c,
                                                 float* __restrict__ out) {
    int i = blockIdx.x * 256 + threadIdx.x;
    float v = (i < 1024) ? a[i] : (i < 2048) ? b[i - 1024] : c[i - 2048];
    out[i] = v;
}

// ---------------- transpose fp32 [R][C] -> bf16 [C][R] ----------------
__global__ __launch_bounds__(256) void k_transpose_f32_bf16(const float* __restrict__ src,
                                                            unsigned short* __restrict__ dst,
                                                            int R, int C) {
    __shared__ unsigned short t[64][80];
    int r0 = blockIdx.x * 64, c0 = blockIdx.y * 64;
    int tid = threadIdx.x;
    int rr = tid >> 4, cc = (tid & 15) << 2;
#pragma unroll
    for (int p = 0; p < 4; ++p) {
        int r = rr + p * 16;
        float4 v = *(const float4*)(src + (size_t)(r0 + r) * C + c0 + cc);
        t[cc + 0][r] = f2bf(v.x);
        t[cc + 1][r] = f2bf(v.y);
        t[cc + 2][r] = f2bf(v.z);
        t[cc + 3][r] = f2bf(v.w);
    }
    __syncthreads();
    int wr = tid >> 3, wc = (tid & 7) << 3;
#pragma unroll
    for (int p = 0; p < 2; ++p) {
        int c = wr + p * 32;
        uint4 v8 = *(const uint4*)&t[c][wc];
        *(uint4*)(dst + (size_t)(c0 + c) * R + r0 + wc) = v8;
    }
}

// ---------------- transpose bf16 [R][C] -> bf16 [C][R] ----------------
__global__ __launch_bounds__(256) void k_transpose_bf16(const unsigned short* __restrict__ src,
                                                        unsigned short* __restrict__ dst,
                                                        int R, int C) {
    __shared__ unsigned short t[64][80];
    int r0 = blockIdx.x * 64, c0 = blockIdx.y * 64;
    int tid = threadIdx.x;
    int rr = tid >> 3, cc = (tid & 7) << 3;
#pragma unroll
    for (int p = 0; p < 2; ++p) {
        int r = rr + p * 32;
        uint4 v = *(const uint4*)(src + (size_t)(r0 + r) * C + c0 + cc);
        const unsigned short* pv = (const unsigned short*)&v;
#pragma unroll
        for (int i = 0; i < 8; ++i) t[cc + i][r] = pv[i];
    }
    __syncthreads();
    int wr = tid >> 3, wc = (tid & 7) << 3;
#pragma unroll
    for (int p = 0; p < 2; ++p) {
        int c = wr + p * 32;
        uint4 v8 = *(const uint4*)&t[c][wc];
        *(uint4*)(dst + (size_t)(c0 + c) * R + r0 + wc) = v8;
    }
}

// ---- LN apply: read bf16 z row [3072], per-chain stats from pS/pQ, write qb/kb/vb ----
__global__ __launch_bounds__(256) void k_ln_apply(const unsigned short* __restrict__ zb,
                                                  const float* __restrict__ pS,
                                                  const float* __restrict__ pQ,
                                                  const float* __restrict__ gq, const float* __restrict__ betaq,
                                                  const float* __restrict__ gk, const float* __restrict__ betak,
                                                  const float* __restrict__ gv, const float* __restrict__ betav,
                                                  unsigned short* __restrict__ qb,
                                                  unsigned short* __restrict__ kb,
                                                  unsigned short* __restrict__ vb) {
    __shared__ float sS[48], sQ[48];
    int row = blockIdx.x, tid = threadIdx.x;
    if (tid < 48) { sS[tid] = pS[(size_t)row * 48 + tid]; sQ[tid] = pQ[(size_t)row * 48 + tid]; }
    __syncthreads();
    float m[3], rs[3];
#pragma unroll
    for (int c = 0; c < 3; ++c) {
        float s = 0.0f, q = 0.0f;
#pragma unroll
        for (int j = 0; j < 16; ++j) { s += sS[c * 16 + j]; q += sQ[c * 16 + j]; }
        float mm = s * (1.0f / D_DIM);
        float var = q * (1.0f / D_DIM) - mm * mm;
        m[c] = mm; rs[c] = rsqrtf(var + 1e-5f);
    }
    const unsigned short* zrow = zb + (size_t)row * 3072;
    const float* gs[3] = {gq, gk, gv};
    const float* bs[3] = {betaq, betak, betav};
    unsigned short* outs[3] = {qb, kb, vb};
#pragma unroll
    for (int c = 0; c < 3; ++c) {
        ushort4 u = *(const ushort4*)(zrow + c * 1024 + tid * 4);
        float4 g4 = *(const float4*)(gs[c] + tid * 4);
        float4 b4 = *(const float4*)(bs[c] + tid * 4);
        ushort4 o;
        o.x = f2bf((bf2f(u.x) - m[c]) * rs[c] * g4.x + b4.x);
        o.y = f2bf((bf2f(u.y) - m[c]) * rs[c] * g4.y + b4.y);
        o.z = f2bf((bf2f(u.z) - m[c]) * rs[c] * g4.z + b4.z);
        o.w = f2bf((bf2f(u.w) - m[c]) * rs[c] * g4.w + b4.w);
        *(ushort4*)(outs[c] + (size_t)row * D_DIM + tid * 4) = o;
    }
}

// ---------------- combine per-tile stats: rmax, rrecip ----------------
__global__ __launch_bounds__(256) void k_stats_reduce(const float* __restrict__ pmax,
                                                      const float* __restrict__ psum,
                                                      float* __restrict__ rmax,
                                                      float* __restrict__ rrecip, int nblk) {
    int row = blockIdx.x * 4 + (threadIdx.x >> 6);
    int lane = threadIdx.x & 63;
    const float* pm = pmax + (size_t)row * nblk;
    const float* ps = psum + (size_t)row * nblk;
    float m = -3.4e38f;
    for (int j = lane; j < nblk; j += 64) m = fmaxf(m, pm[j]);
#pragma unroll
    for (int mk = 32; mk; mk >>= 1) m = fmaxf(m, __shfl_xor(m, mk));
    float s = 0.0f;
    for (int j = lane; j < nblk; j += 64) s += ps[j] * __expf(pm[j] - m);
#pragma unroll
    for (int mk = 32; mk; mk >>= 1) s += __shfl_xor(s, mk);
    if (lane == 0) { rmax[row] = m; rrecip[row] = 1.0f / s; }
}

// ------- normalize: bf16 logits -> fp32 attn + bf16 At -------
__global__ __launch_bounds__(256) void k_norm_transpose(const unsigned short* __restrict__ src16,
                                                        float* __restrict__ attn,
                                                        const float* __restrict__ rmax,
                                                        const float* __restrict__ rrecip,
                                                        unsigned short* __restrict__ At) {
    __shared__ unsigned short t[64][80];
    int t0 = blockIdx.x * 64, s0 = blockIdx.y * 64;
    int tid = threadIdx.x;
    int rr = tid >> 4, cc = (tid & 15) << 2;
#pragma unroll
    for (int p = 0; p < 4; ++p) {
        int r = rr + p * 16;
        float m = rmax[t0 + r], rc = rrecip[t0 + r];
        size_t off = (size_t)(t0 + r) * S_SEQ + s0 + cc;
        ushort4 u = *(const ushort4*)(src16 + off);
        float4 v;
        v.x = __expf(bf2f(u.x) - m) * rc;
        v.y = __expf(bf2f(u.y) - m) * rc;
        v.z = __expf(bf2f(u.z) - m) * rc;
        v.w = __expf(bf2f(u.w) - m) * rc;
        *(float4*)(attn + off) = v;
        t[cc + 0][r] = f2bf(v.x);
        t[cc + 1][r] = f2bf(v.y);
        t[cc + 2][r] = f2bf(v.z);
        t[cc + 3][r] = f2bf(v.w);
    }
    __syncthreads();
    int wr = tid >> 3, wc = (tid & 7) << 3;
#pragma unroll
    for (int p = 0; p < 2; ++p) {
        int c = wr + p * 32;
        uint4 v8 = *(const uint4*)&t[c][wc];
        *(uint4*)(At + (size_t)(s0 + c) * S_SEQ + t0 + wc) = v8;
    }
}

// ---------------- classifier: c = x @ Wc + bc ----------------
__global__ __launch_bounds__(256) void k_classifier(const float* __restrict__ x,
                                                    const float* __restrict__ Wc,
                                                    const float* __restrict__ bc,
                                                    float* __restrict__ outc) {
    __shared__ float red[4][NCLS];
    int row = blockIdx.x, tid = threadIdx.x;
    float4 xv = *(const float4*)(x + (size_t)row * D_DIM + tid * 4);
    const float* w0 = Wc + (size_t)(tid * 4) * NCLS;
    float acc[NCLS];
#pragma unroll
    for (int j = 0; j < NCLS; ++j)
        acc[j] = xv.x * w0[j] + xv.y * w0[NCLS + j] + xv.z * w0[2 * NCLS + j] + xv.w * w0[3 * NCLS + j];
#pragma unroll
    for (int j = 0; j < NCLS; ++j)
#pragma unroll
        for (int o = 32; o; o >>= 1) acc[j] += __shfl_down(acc[j], o);
    int lane = tid & 63, wv = tid >> 6;
    if (lane == 0) {
#pragma unroll
        for (int j = 0; j < NCLS; ++j) red[wv][j] = acc[j];
    }
    __syncthreads();
    if (tid < NCLS) {
        float s = red[0][tid] + red[1][tid] + red[2][tid] + red[3][tid];
        outc[(size_t)row * NCLS + tid] = s + bc[tid];
    }
}

// ======== shared pieces for 8-phase GEMM ========
#define BAR()  __builtin_amdgcn_s_barrier()
#define LGKM0() asm volatile("s_waitcnt lgkmcnt(0)" ::: "memory")
#define VMW(n) asm volatile("s_waitcnt vmcnt(%0)" :: "n"(n) : "memory")

#define LD_A8(db, q, ii, ks) \
    (*(const bf16x8*)&lds[db][0][wm][((q)*32 + (ii)*16 + fm) * 64 + ((((ks)*32 + g*8)) ^ ((((q)*32 + (ii)*16 + fm) & 7) << 3))])
#define LD_B8(db, j, ks) \
    (*(const bf16x8*)&lds[db][1][wn >> 1][((wn & 1)*64 + (j)*16 + fm) * 64 + ((((ks)*32 + g*8)) ^ (((((wn & 1)*64 + (j)*16 + fm)) & 7) << 3))])

#define MFMA16(q, a00, a10, a01, a11)                                                          \
    {                                                                                          \
        __builtin_amdgcn_s_setprio(1);                                                         \
        _Pragma("unroll")                                                                      \
        for (int j = 0; j < 4; ++j) {                                                          \
            acc[(q)*2 + 0][j] = __builtin_amdgcn_mfma_f32_16x16x32_bf16(a00, breg[j][0], acc[(q)*2 + 0][j], 0, 0, 0); \
            acc[(q)*2 + 1][j] = __builtin_amdgcn_mfma_f32_16x16x32_bf16(a10, breg[j][0], acc[(q)*2 + 1][j], 0, 0, 0); \
            acc[(q)*2 + 0][j] = __builtin_amdgcn_mfma_f32_16x16x32_bf16(a01, breg[j][1], acc[(q)*2 + 0][j], 0, 0, 0); \
            acc[(q)*2 + 1][j] = __builtin_amdgcn_mfma_f32_16x16x32_bf16(a11, breg[j][1], acc[(q)*2 + 1][j], 0, 0, 0); \
        }                                                                                      \
        __builtin_amdgcn_s_setprio(0);                                                         \
    }

// ======== 8-phase 256x256 GEMM (non-persistent). EPI: 0=fp32+bias, 3=bf16+bias+LN-stats ========
template<int SK, int EPI>
__global__ __launch_bounds__(512) void k_gemm_8ph(const unsigned short* __restrict__ A,
                                                  const unsigned short* __restrict__ B,
                                                  float* __restrict__ C0,
                                                  float* __restrict__ C1,
                                                  unsigned short* __restrict__ Cb,
                                                  int M, int N, int K, float scale,
                                                  const float* __restrict__ bias,
                                                  float* __restrict__ pS,
                                                  float* __restrict__ pQ) {
    __shared__ unsigned short lds[2][2][2][8192];

    const int tid = threadIdx.x;
    const int lane = tid & 63;
    const int wid = tid >> 6;
    const int wm = wid >> 2;
    const int wn = wid & 3;
    const int fm = lane & 15;
    const int g = lane >> 4;

    const int nbm = M >> 8;
    const int nbn = N >> 8;
    int bm, bn, sk;
    if ((gridDim.x & 7) == 0) {
        int wg = (blockIdx.x & 7) * (gridDim.x >> 3) + (blockIdx.x >> 3);
        sk = wg / (nbm * nbn);
        int rem = wg % (nbm * nbn);
        bm = rem / nbn;
        bn = rem % nbn;
    } else {
        bm = blockIdx.x / nbn; bn = blockIdx.x % nbn; sk = 0;
    }
    const int brow = bm << 8;
    const int bcol = bn << 8;
    const int Ksub = K / SK;
    const int koff = sk * Ksub;
    const int NKT = Ksub >> 6;
    const int NI = NKT >> 1;
    float* __restrict__ C = (SK == 2 && sk == 1) ? C1 : C0;

    const int srow = tid >> 3;
    const int scol = ((tid & 7) << 3) ^ ((srow & 7) << 3);

    auto stA = [&](int kt, int h) {
        const unsigned short* s = A + (size_t)(brow + h * 128 + srow) * K + koff + kt * 64 + scol;
        unsigned short* d = &lds[kt & 1][0][h][tid * 8];
        GLL(s, d);
        GLL(s + (size_t)64 * K, d + 4096);
    };
    auto stB = [&](int kt, int h) {
        const unsigned short* s = B + (size_t)(bcol + h * 128 + srow) * K + koff + kt * 64 + scol;
        unsigned short* d = &lds[kt & 1][1][h][tid * 8];
        GLL(s, d);
        GLL(s + (size_t)64 * K, d + 4096);
    };

    f32x4 acc[8][4] = {};
    bf16x8 breg[4][2];

    stB(0, 0); stB(0, 1);
    stA(0, 0); stA(0, 1);
    stB(1, 0); stB(1, 1);
    VMW(4);
    BAR();

    for (int it = 0; it < NI; ++it) {
        const int kt1 = 2 * it + 1;
        const bool pfA = (2 * it + 2) < NKT;
        const bool pfB = (2 * it + 3) < NKT;

        {
            bf16x8 a00 = LD_A8(0, 0, 0, 0), a10 = LD_A8(0, 0, 1, 0);
            bf16x8 a01 = LD_A8(0, 0, 0, 1), a11 = LD_A8(0, 0, 1, 1);
#pragma unroll
            for (int j = 0; j < 4; ++j) { breg[j][0] = LD_B8(0, j, 0); breg[j][1] = LD_B8(0, j, 1); }
            stA(kt1, 0);
            BAR(); LGKM0();
            MFMA16(0, a00, a10, a01, a11);
            BAR();
        }
        {
            bf16x8 a00 = LD_A8(0, 1, 0, 0), a10 = LD_A8(0, 1, 1, 0);
            bf16x8 a01 = LD_A8(0, 1, 0, 1), a11 = LD_A8(0, 1, 1, 1);
            stA(kt1, 1);
            if (pfA) stB(2 * it + 2, 0);
            BAR(); LGKM0();
            MFMA16(1, a00, a10, a01, a11);
            BAR();
        }
        {
            bf16x8 a00 = LD_A8(0, 2, 0, 0), a10 = LD_A8(0, 2, 1, 0);
            bf16x8 a01 = LD_A8(0, 2, 0, 1), a11 = LD_A8(0, 2, 1, 1);
            if (pfA) stB(2 * it + 2, 1);
            BAR(); LGKM0();
            MFMA16(2, a00, a10, a01, a11);
            BAR();
        }
        {
            bf16x8 a00 = LD_A8(0, 3, 0, 0), a10 = LD_A8(0, 3, 1, 0);
            bf16x8 a01 = LD_A8(0, 3, 0, 1), a11 = LD_A8(0, 3, 1, 1);
            BAR(); LGKM0();
            MFMA16(3, a00, a10, a01, a11);
            if (pfA) { VMW(4); } else { VMW(0); }
            BAR();
        }
        {
            bf16x8 a00 = LD_A8(1, 0, 0, 0), a10 = LD_A8(1, 0, 1, 0);
            bf16x8 a01 = LD_A8(1, 0, 0, 1), a11 = LD_A8(1, 0, 1, 1);
#pragma unroll
            for (int j = 0; j < 4; ++j) { breg[j][0] = LD_B8(1, j, 0); breg[j][1] = LD_B8(1, j, 1); }
            if (pfA) stA(2 * it + 2, 0);
            BAR(); LGKM0();
            MFMA16(0, a00, a10, a01, a11);
            BAR();
        }
        {
            bf16x8 a00 = LD_A8(1, 1, 0, 0), a10 = LD_A8(1, 1, 1, 0);
            bf16x8 a01 = LD_A8(1, 1, 0, 1), a11 = LD_A8(1, 1, 1, 1);
            if (pfA) stA(2 * it + 2, 1);
            if (pfB) stB(2 * it + 3, 0);
            BAR(); LGKM0();
            MFMA16(1, a00, a10, a01, a11);
            BAR();
        }
        {
            bf16x8 a00 = LD_A8(1, 2, 0, 0), a10 = LD_A8(1, 2, 1, 0);
            bf16x8 a01 = LD_A8(1, 2, 0, 1), a11 = LD_A8(1, 2, 1, 1);
            if (pfB) stB(2 * it + 3, 1);
            BAR(); LGKM0();
            MFMA16(2, a00, a10, a01, a11);
            BAR();
        }
        {
            bf16x8 a00 = LD_A8(1, 3, 0, 0), a10 = LD_A8(1, 3, 1, 0);
            bf16x8 a01 = LD_A8(1, 3, 0, 1), a11 = LD_A8(1, 3, 1, 1);
            BAR(); LGKM0();
            MFMA16(3, a00, a10, a01, a11);
            if (it + 1 < NI) {
                if (pfB) { VMW(4); } else { VMW(0); }
            }
            BAR();
        }
    }

    if constexpr (EPI == 3) {
        // bf16 z store with bias + LN partial sums per (row, 64-col block)
        const int nblk = N >> 6;
        const int cblk = (bcol >> 6) + wn;
        float bj[4];
#pragma unroll
        for (int j = 0; j < 4; ++j) bj[j] = bias[bcol + wn * 64 + j * 16 + fm];
#pragma unroll
        for (int i = 0; i < 8; ++i) {
#pragma unroll
            for (int r = 0; r < 4; ++r) {
                float z[4];
#pragma unroll
                for (int j = 0; j < 4; ++j) z[j] = acc[i][j][r] * scale + bj[j];
                float s = z[0] + z[1] + z[2] + z[3];
                float q = z[0] * z[0] + z[1] * z[1] + z[2] * z[2] + z[3] * z[3];
#pragma unroll
                for (int mk = 1; mk < 16; mk <<= 1) { s += __shfl_xor(s, mk); q += __shfl_xor(q, mk); }
                int row = brow + wm * 128 + i * 16 + (g << 2) + r;
                if (fm == 0) {
                    pS[(size_t)row * nblk + cblk] = s;
                    pQ[(size_t)row * nblk + cblk] = q;
                }
#pragma unroll
                for (int j = 0; j < 4; ++j)
                    Cb[(size_t)row * N + bcol + wn * 64 + j * 16 + fm] = f2bf(z[j]);
            }
        }
    } else {
#pragma unroll
        for (int i = 0; i < 8; ++i) {
#pragma unroll
            for (int j = 0; j < 4; ++j) {
                int col = bcol + wn * 64 + j * 16 + fm;
                float badd = bias ? bias[col] : 0.0f;
#pragma unroll
                for (int r = 0; r < 4; ++r) {
                    int row = brow + wm * 128 + i * 16 + (g << 2) + r;
                    C[(size_t)row * N + col] = acc[i][j][r] * scale + badd;
                }
            }
        }
    }
}

// ======== persistent QK^T: 4 bm-tiles per block at fixed bn, prologue/epilogue overlap ========
// grid = 256 (1 block/CU). M=N=8192, K=1024 (NKT=16, NI=8). bf16 out + softmax stats.
__global__ __launch_bounds__(512) void k_qkt_8ph(const unsigned short* __restrict__ A,
                                                 const unsigned short* __restrict__ B,
                                                 unsigned short* __restrict__ Cb,
                                                 float scale,
                                                 float* __restrict__ pmax,
                                                 float* __restrict__ psum) {
    __shared__ unsigned short lds[2][2][2][8192];
    const int K = D_DIM, N = S_SEQ;
    const int NKT = 16, NI = 8, REPS = 4;

    const int tid = threadIdx.x;
    const int lane = tid & 63;
    const int wid = tid >> 6;
    const int wm = wid >> 2;
    const int wn = wid & 3;
    const int fm = lane & 15;
    const int g = lane >> 4;

    // mapping: xcd-partitioned bn (4 bn per XCD), bmbase 0..7, bm = bmbase + 8*rep
    const int xcd = blockIdx.x & 7;
    const int c = blockIdx.x >> 3;
    const int bn = xcd * 4 + (c & 3);
    const int bmbase = c >> 2;
    const int bcol = bn << 8;

    const int srow = tid >> 3;
    const int scol = ((tid & 7) << 3) ^ ((srow & 7) << 3);

    const unsigned short* gB = B + (size_t)(bcol + srow) * K + scol;
    auto gArep = [&](int rep) {
        return A + (size_t)(((bmbase + 8 * rep) << 8) + srow) * K + scol;
    };

    auto st = [&](const unsigned short* gb, int kt, int ab, int h) {
        const unsigned short* s = gb + (size_t)(h * 128) * K + kt * 64;
        unsigned short* d = &lds[kt & 1][ab][h][tid * 8];
        GLL(s, d);
        GLL(s + (size_t)64 * K, d + 4096);
    };

    f32x4 acc[8][4];
    bf16x8 breg[4][2];

    // initial prologue (rep 0)
    const unsigned short* gA0 = gArep(0);
    st(gB, 0, 1, 0); st(gB, 0, 1, 1);
    st(gA0, 0, 0, 0); st(gA0, 0, 0, 1);
    st(gB, 1, 1, 0); st(gB, 1, 1, 1);
    VMW(4);
    BAR();

    for (int rep = 0; rep < REPS; ++rep) {
        const unsigned short* gAc = gArep(rep);
        const unsigned short* gAn = gArep(rep + 1 < REPS ? rep + 1 : rep);
        const bool nrep = (rep + 1) < REPS;
        const int brow = (bmbase + 8 * rep) << 8;

#pragma unroll
        for (int i = 0; i < 8; ++i)
#pragma unroll
            for (int j = 0; j < 4; ++j) acc[i][j] = (f32x4){0.0f, 0.0f, 0.0f, 0.0f};

        for (int it = 0; it < NI; ++it) {
            const int kt1 = 2 * it + 1;
            const bool pfA = (2 * it + 2) < NKT;
            const bool pfB = (2 * it + 3) < NKT;

            // phase 1 (dbuf0, q0)
            {
                bf16x8 a00 = LD_A8(0, 0, 0, 0), a10 = LD_A8(0, 0, 1, 0);
                bf16x8 a01 = LD_A8(0, 0, 0, 1), a11 = LD_A8(0, 0, 1, 1);
#pragma unroll
                for (int j = 0; j < 4; ++j) { breg[j][0] = LD_B8(0, j, 0); breg[j][1] = LD_B8(0, j, 1); }
                st(gAc, kt1, 0, 0);
                BAR(); LGKM0();
                MFMA16(0, a00, a10, a01, a11);
                BAR();
            }
            // phase 2 (dbuf0, q1): B(2it+2) or next-rep B(0)
            {
                bf16x8 a00 = LD_A8(0, 1, 0, 0), a10 = LD_A8(0, 1, 1, 0);
                bf16x8 a01 = LD_A8(0, 1, 0, 1), a11 = LD_A8(0, 1, 1, 1);
                st(gAc, kt1, 0, 1);
                if (pfA) st(gB, 2 * it + 2, 1, 0);
                else if (nrep) st(gB, 0, 1, 0);
                BAR(); LGKM0();
                MFMA16(1, a00, a10, a01, a11);
                BAR();
            }
            // phase 3 (dbuf0, q2)
            {
                bf16x8 a00 = LD_A8(0, 2, 0, 0), a10 = LD_A8(0, 2, 1, 0);
                bf16x8 a01 = LD_A8(0, 2, 0, 1), a11 = LD_A8(0, 2, 1, 1);
                if (pfA) st(gB, 2 * it + 2, 1, 1);
                else if (nrep) st(gB, 0, 1, 1);
                BAR(); LGKM0();
                MFMA16(2, a00, a10, a01, a11);
                BAR();
            }
            // phase 4 (dbuf0, q3) + vmcnt: dbuf1 (tile kt1) must be resident
            {
                bf16x8 a00 = LD_A8(0, 3, 0, 0), a10 = LD_A8(0, 3, 1, 0);
                bf16x8 a01 = LD_A8(0, 3, 0, 1), a11 = LD_A8(0, 3, 1, 1);
                BAR(); LGKM0();
                MFMA16(3, a00, a10, a01, a11);
                if (pfA || nrep) { VMW(4); } else { VMW(0); }
                BAR();
            }
            // phase 5 (dbuf1, q0): A(2it+2) or next-rep A(0)
            {
                bf16x8 a00 = LD_A8(1, 0, 0, 0), a10 = LD_A8(1, 0, 1, 0);
                bf16x8 a01 = LD_A8(1, 0, 0, 1), a11 = LD_A8(1, 0, 1, 1);
#pragma unroll
                for (int j = 0; j < 4; ++j) { breg[j][0] = LD_B8(1, j, 0); breg[j][1] = LD_B8(1, j, 1); }
                if (pfA) st(gAc, 2 * it + 2, 0, 0);
                else if (nrep) st(gAn, 0, 0, 0);
                BAR(); LGKM0();
                MFMA16(0, a00, a10, a01, a11);
                BAR();
            }
            // phase 6 (dbuf1, q1)
            {
                bf16x8 a00 = LD_A8(1, 1, 0, 0), a10 = LD_A8(1, 1, 1, 0);
                bf16x8 a01 = LD_A8(1, 1, 0, 1), a11 = LD_A8(1, 1, 1, 1);
                if (pfA) st(gAc, 2 * it + 2, 0, 1);
                else if (nrep) st(gAn, 0, 0, 1);
                if (pfB) st(gB, 2 * it + 3, 1, 0);
                else if (nrep) st(gB, 1, 1, 0);
                BAR(); LGKM0();
                MFMA16(1, a00, a10, a01, a11);
                BAR();
            }
            // phase 7 (dbuf1, q2)
            {
                bf16x8 a00 = LD_A8(1, 2, 0, 0), a10 = LD_A8(1, 2, 1, 0);
                bf16x8 a01 = LD_A8(1, 2, 0, 1), a11 = LD_A8(1, 2, 1, 1);
                if (pfB) st(gB, 2 * it + 3, 1, 1);
                else if (nrep) st(gB, 1, 1, 1);
                BAR(); LGKM0();
                MFMA16(2, a00, a10, a01, a11);
                BAR();
            }
            // phase 8 (dbuf1, q3) + vmcnt
            {
                bf16x8 a00 = LD_A8(1, 3, 0, 0), a10 = LD_A8(1, 3, 1, 0);
                bf16x8 a01 = LD_A8(1, 3, 0, 1), a11 = LD_A8(1, 3, 1, 1);
                BAR(); LGKM0();
                MFMA16(3, a00, a10, a01, a11);
                if (it + 1 < NI) { VMW(4); }
                else if (nrep) { VMW(4); }   // next-rep tile0 resident; B(1) in flight
                BAR();
            }
        }

        // per-rep epilogue: softmax stats + bf16 store (overlaps next-rep loads in flight)
        {
            const int nblk = N >> 6;
            const int cblk = (bcol >> 6) + wn;
#pragma unroll
            for (int i = 0; i < 8; ++i) {
#pragma unroll
                for (int r = 0; r < 4; ++r) {
                    float v0 = acc[i][0][r] * scale, v1 = acc[i][1][r] * scale;
                    float v2 = acc[i][2][r] * scale, v3 = acc[i][3][r] * scale;
                    float mv = fmaxf(fmaxf(v0, v1), fmaxf(v2, v3));
#pragma unroll
                    for (int mk = 1; mk < 16; mk <<= 1) mv = fmaxf(mv, __shfl_xor(mv, mk));
                    float sv = __expf(v0 - mv) + __expf(v1 - mv) + __expf(v2 - mv) + __expf(v3 - mv);
#pragma unroll
                    for (int mk = 1; mk < 16; mk <<= 1) sv += __shfl_xor(sv, mk);
                    int row = brow + wm * 128 + i * 16 + (g << 2) + r;
                    if (fm == 0) {
                        pmax[(size_t)row * nblk + cblk] = mv;
                        psum[(size_t)row * nblk + cblk] = sv;
                    }
                    Cb[(size_t)row * N + bcol + wn * 64 + 0 * 16 + fm] = f2bf(v0);
                    Cb[(size_t)row * N + bcol + wn * 64 + 1 * 16 + fm] = f2bf(v1);
                    Cb[(size_t)row * N + bcol + wn * 64 + 2 * 16 + fm] = f2bf(v2);
                    Cb[(size_t)row * N + bcol + wn * 64 + 3 * 16 + fm] = f2bf(v3);
                }
            }
        }
    }
}

// ============ pipelined bf16 GEMM (old structure, kept for o-GEMM) ============
template<int BN, int WM, int WN, int NSLOT>
__global__ __launch_bounds__(512) void k_gemm_big(const unsigned short* __restrict__ A,
                                                  const unsigned short* __restrict__ B,
                                                  float* __restrict__ C,
                                                  int M, int N, int K,
                                                  float scale,
                                                  const float* __restrict__ bias) {
    constexpr int MREP = 256 / WM / 16;
    constexpr int NREP = BN / WN / 16;
    constexpr int PHASES = MREP / 4;
    constexpr int BISS = BN / 128;
    constexpr int TISS = 2 + BISS;
    constexpr int DEPTH = NSLOT - 1;
    constexpr int ASLOT = 256 * 32;
    constexpr int BSLOT = BN * 32;
    constexpr int SLOT = ASLOT + BSLOT;
    __shared__ unsigned short lds[NSLOT * SLOT];

    const int tid = threadIdx.x;
    const int lane = tid & 63;
    const int wid = tid >> 6;
    const int wm = wid / WN;
    const int wn = wid % WN;
    const int fm = lane & 15;
    const int g = lane >> 4;

    const int nbn = N / BN;
    int bm, bn;
    if ((gridDim.x & 7) == 0) {
        int wg = (blockIdx.x & 7) * (gridDim.x >> 3) + (blockIdx.x >> 3);
        bm = wg / nbn; bn = wg % nbn;
    } else {
        bm = blockIdx.x / nbn; bn = blockIdx.x % nbn;
    }
    const int brow = bm << 8;
    const int bcol = bn * BN;
    const int NT = K >> 5;

    const int arow = tid >> 2;
    const int scb = ((tid & 3) << 4) ^ ((arow & 6) << 3);
    const unsigned short* gA = A + (size_t)(brow + arow) * K + (scb >> 1);
    const unsigned short* gB = B + (size_t)(bcol + arow) * K + (scb >> 1);
    unsigned short* lA = lds + tid * 8;
    unsigned short* lB = lds + ASLOT + tid * 8;
    const size_t rows128 = (size_t)128 * K;

    auto stageA = [&](int kt, int slot) {
        const unsigned short* s = gA + ((size_t)kt << 5);
        unsigned short* d = lA + slot * SLOT;
        GLL(s, d);
        GLL(s + rows128, d + 4096);
    };
    auto stageB = [&](int kt, int slot) {
        const unsigned short* s = gB + ((size_t)kt << 5);
        unsigned short* d = lB + slot * SLOT;
#pragma unroll
        for (int h = 0; h < BISS; ++h)
            GLL(s + (size_t)h * rows128, d + h * 4096);
    };

    const int cbf = (((g << 4) ^ ((fm & 6) << 3)) >> 1);
    const unsigned short* fA = lds + (wm * (256 / WM) + fm) * 32 + cbf;
    const unsigned short* fB = lds + ASLOT + (wn * (BN / WN) + fm) * 32 + cbf;

    f32x4 acc[MREP][NREP] = {};

#pragma unroll
    for (int p = 0; p < DEPTH; ++p) { stageA(p, p); stageB(p, p); }
    asm volatile("s_waitcnt vmcnt(%0)" :: "n"((DEPTH - 1) * TISS) : "memory");
    __builtin_amdgcn_s_barrier();

    for (int t = 0; t < NT; ++t) {
        const int slot = t % NSLOT;
        const unsigned short* sA = fA + slot * SLOT;
        const unsigned short* sB = fB + slot * SLOT;
        const int pslot = (t + DEPTH) % NSLOT;
        const bool pf = (t + DEPTH) < NT;

        bf16x8 bfr[NREP];
        bf16x8 afr[4];
#pragma unroll
        for (int i = 0; i < 4; ++i) afr[i] = *(const bf16x8*)(sA + i * 512);
#pragma unroll
        for (int j = 0; j < NREP; ++j) bfr[j] = *(const bf16x8*)(sB + j * 512);
        if (pf) {
            stageA(t + DEPTH, pslot);
            if (PHASES == 1) stageB(t + DEPTH, pslot);
        }
        __builtin_amdgcn_s_barrier();
        asm volatile("s_waitcnt lgkmcnt(0)" ::: "memory");
        __builtin_amdgcn_s_setprio(1);
#pragma unroll
        for (int i = 0; i < 4; ++i)
#pragma unroll
            for (int j = 0; j < NREP; ++j)
                acc[i][j] = __builtin_amdgcn_mfma_f32_16x16x32_bf16(afr[i], bfr[j], acc[i][j], 0, 0, 0);
        __builtin_amdgcn_s_setprio(0);
        __builtin_amdgcn_s_barrier();

        if (PHASES == 2) {
#pragma unroll
            for (int i = 0; i < 4; ++i) afr[i] = *(const bf16x8*)(sA + (i + 4) * 512);
            if (pf) stageB(t + DEPTH, pslot);
            __builtin_amdgcn_s_barrier();
            asm volatile("s_waitcnt lgkmcnt(0)" ::: "memory");
            __builtin_amdgcn_s_setprio(1);
#pragma unroll
            for (int i = 0; i < 4; ++i)
#pragma unroll
                for (int j = 0; j < NREP; ++j)
                    acc[(i + 4) % MREP][j] = __builtin_amdgcn_mfma_f32_16x16x32_bf16(afr[i], bfr[j], acc[(i + 4) % MREP][j], 0, 0, 0);
            __builtin_amdgcn_s_setprio(0);
        }

        if (t + 1 < NT) {
            if (t + DEPTH < NT)
                asm volatile("s_waitcnt vmcnt(%0)" :: "n"(TISS) : "memory");
            else
                asm volatile("s_waitcnt vmcnt(0)" ::: "memory");
        }
        __builtin_amdgcn_s_barrier();
    }

    const int r0 = g << 2;
#pragma unroll
    for (int i = 0; i < MREP; ++i)
#pragma unroll
        for (int j = 0; j < NREP; ++j) {
            int col = bcol + wn * (BN / WN) + j * 16 + fm;
            float badd = bias ? bias[col] : 0.0f;
#pragma unroll
            for (int r = 0; r < 4; ++r) {
                int row = brow + wm * (256 / WM) + i * 16 + r0 + r;
                C[(size_t)row * N + col] = acc[i][j][r] * scale + badd;
            }
        }
}

extern "C" void kernel_launch(void* const* d_in, const int* in_sizes, int n_in,
                              void* d_out, int out_size, void* d_ws, size_t ws_size,
                              hipStream_t stream) {
    const float* x     = (const float*)d_in[0];
    const float* Wq    = (const float*)d_in[1];
    const float* bq    = (const float*)d_in[2];
    const float* gq    = (const float*)d_in[3];
    const float* betaq = (const float*)d_in[4];
    const float* Wk    = (const float*)d_in[5];
    const float* bk    = (const float*)d_in[6];
    const float* gk    = (const float*)d_in[7];
    const float* betak = (const float*)d_in[8];
    const float* Wv    = (const float*)d_in[9];
    const float* bv    = (const float*)d_in[10];
    const float* gv    = (const float*)d_in[11];
    const float* betav = (const float*)d_in[12];
    const float* Wo    = (const float*)d_in[13];
    const float* bo    = (const float*)d_in[14];
    const float* Wc    = (const float*)d_in[15];
    const float* bc    = (const float*)d_in[16];

    float* out_o    = (float*)d_out;
    float* out_c    = out_o + (size_t)S_SEQ * D_DIM;
    float* out_attn = out_c + (size_t)S_SEQ * NCLS;

    char* cur = (char*)d_ws;
    auto alloc = [&](size_t bytes) {
        char* p = cur;
        cur += (bytes + 255) & ~(size_t)255;
        return p;
    };
    const size_t SD2 = (size_t)S_SEQ * D_DIM * 2;
    const size_t DD2 = (size_t)D_DIM * D_DIM * 2;
    unsigned short* xb   = (unsigned short*)alloc(SD2);
    unsigned short* wqkv = (unsigned short*)alloc(3 * DD2);
    unsigned short* wto  = (unsigned short*)alloc(DD2);
    unsigned short* qb   = (unsigned short*)alloc(SD2);
    unsigned short* kb   = (unsigned short*)alloc(SD2);
    unsigned short* vb   = (unsigned short*)alloc(SD2);
    unsigned short* Vt   = (unsigned short*)alloc(SD2);
    unsigned short* valb = (unsigned short*)alloc(SD2);
    float* rmax   = (float*)alloc((size_t)S_SEQ * 4);
    float* rrecip = (float*)alloc((size_t)S_SEQ * 4);
    float* bqkv   = (float*)alloc((size_t)3 * D_DIM * 4);
    float* pS     = (float*)alloc((size_t)S_SEQ * 48 * 4);
    float* pQ     = (float*)alloc((size_t)S_SEQ * 48 * 4);
    unsigned short* At = (unsigned short*)alloc((size_t)S_SEQ * S_SEQ * 2);
    unsigned short* Lb = (unsigned short*)alloc((size_t)S_SEQ * S_SEQ * 2);

    // overlays: QK^T softmax partial stats over xb (dead after QKV GEMM);
    // split-K partial over qb+kb (dead after QK^T; 32 MB exactly).
    float* pmax = (float*)xb;
    float* psum = pmax + (size_t)S_SEQ * 128;
    float* part1 = (float*)qb;
    // QKV bf16 z lives in the (not-yet-written) attention output region.
    unsigned short* zb = (unsigned short*)out_attn;

    const int n4_xd = S_SEQ * D_DIM / 4;

    // x -> bf16
    k_f32_to_bf16<<<n4_xd / 256, 256, 0, stream>>>(x, xb, n4_xd);
    // weight transposes: fp32 [K][N] -> bf16 [N][K]; q/k/v concatenated along N
    k_transpose_f32_bf16<<<dim3(16, 16), 256, 0, stream>>>(Wq, wqkv, D_DIM, D_DIM);
    k_transpose_f32_bf16<<<dim3(16, 16), 256, 0, stream>>>(Wk, wqkv + (size_t)D_DIM * D_DIM, D_DIM, D_DIM);
    k_transpose_f32_bf16<<<dim3(16, 16), 256, 0, stream>>>(Wv, wqkv + (size_t)2 * D_DIM * D_DIM, D_DIM, D_DIM);
    k_transpose_f32_bf16<<<dim3(16, 16), 256, 0, stream>>>(Wo, wto, D_DIM, D_DIM);
    k_concat3<<<12, 256, 0, stream>>>(bq, bk, bv, bqkv);
    // classifier (independent)
    k_classifier<<<S_SEQ, 256, 0, stream>>>(x, Wc, bc, out_c);

    // fused QKV GEMM (8-phase, EPI=3): bf16 z + bias + LN partial sums
    k_gemm_8ph<1, 3><<<(S_SEQ / 256) * (3 * D_DIM / 256), 512, 0, stream>>>(
        xb, wqkv, nullptr, nullptr, zb, S_SEQ, 3 * D_DIM, D_DIM, 1.0f, bqkv, pS, pQ);
    // LN apply: bf16 z -> qb/kb/vb
    k_ln_apply<<<S_SEQ, 256, 0, stream>>>(zb, pS, pQ, gq, betaq, gk, betak, gv, betav, qb, kb, vb);

    // V^T for the A^T V GEMM
    k_transpose_bf16<<<dim3(S_SEQ / 64, D_DIM / 64), 256, 0, stream>>>(vb, Vt, S_SEQ, D_DIM);

    // logits = q k^T / 32 -> bf16 Lb (persistent 8-phase), fused softmax stats
    k_qkt_8ph<<<256, 512, 0, stream>>>(qb, kb, Lb, 0.03125f, pmax, psum);

    // combine stats, then normalize -> fp32 attention output + bf16 At
    k_stats_reduce<<<S_SEQ / 4, 256, 0, stream>>>(pmax, psum, rmax, rrecip, S_SEQ / 64);
    k_norm_transpose<<<dim3(S_SEQ / 64, S_SEQ / 64), 256, 0, stream>>>(
        Lb, out_attn, rmax, rrecip, At);

    // values = A^T V (8-phase, split-K=2: sk0 -> out_o scratch, sk1 -> part1), sum -> bf16
    k_gemm_8ph<2, 0><<<2 * (S_SEQ / 256) * (D_DIM / 256), 512, 0, stream>>>(
        At, Vt, out_o, part1, nullptr, S_SEQ, D_DIM, S_SEQ, 1.0f, nullptr, nullptr, nullptr);
    k_sum2_bf16<<<n4_xd / 256, 256, 0, stream>>>(out_o, part1, valb, n4_xd);

    // o = values @ Wo + bo (old structure)
    k_gemm_big<128, 4, 2, 3><<<(S_SEQ / 256) * (D_DIM / 128), 512, 0, stream>>>(
        valb, wto, out_o, S_SEQ, D_DIM, D_DIM, 1.0f, bo);
}